// Round 3
// baseline (1689.259 us; speedup 1.0000x reference)
//
#include <hip/hip_runtime.h>
#include <hip/hip_bf16.h>
#include <math.h>

typedef __hip_bfloat16 bf16;

__device__ __forceinline__ float b2f(bf16 v){ return __bfloat162float(v); }
__device__ __forceinline__ bf16  f2b(float v){ return __float2bfloat16(v); }
__device__ __forceinline__ float toF(float v){ return v; }
__device__ __forceinline__ float toF(bf16 v){ return __bfloat162float(v); }

#define B_ 16
#define T_ 24
#define N_ 512
#define D_ 64
#define F_ 256

__device__ __forceinline__ float wave_sum(float v){
#pragma unroll
  for (int off = 32; off > 0; off >>= 1) v += __shfl_xor(v, off, 64);
  return v;
}

// ---------- degree^-1/2 ----------
__global__ __launch_bounds__(64) void k_dinv(const float* __restrict__ adj,
                                             float* __restrict__ dinv){
  int m = blockIdx.x;
  float s = 0.f;
  for (int n = threadIdx.x; n < N_; n += 64) s += adj[m*N_ + n];
  s = wave_sum(s);
  if (threadIdx.x == 0){
    float deg = s + 1.0f;               // + identity diagonal
    dinv[m] = rsqrtf(fmaxf(deg, 1e-12f));
  }
}

// ---------- Ahat = dinv_m * (adj + I) * dinv_n ----------
__global__ __launch_bounds__(256) void k_ahat(const float* __restrict__ adj,
                                              const float* __restrict__ dinv,
                                              float* __restrict__ Ahat){
  int idx = blockIdx.x*256 + threadIdx.x;
  int m = idx >> 9, n = idx & (N_-1);
  float a = adj[idx] + (m == n ? 1.f : 0.f);
  Ahat[idx] = dinv[m]*a*dinv[n];
}

// ---------- fused temporal attention + Wo + residual + LN -> h1 (in d_out) ----------
__global__ __launch_bounds__(256) void k_attn(
    const float* __restrict__ x,
    const float* __restrict__ Wq, const float* __restrict__ bq,
    const float* __restrict__ Wk, const float* __restrict__ bk,
    const float* __restrict__ Wv, const float* __restrict__ bv,
    const float* __restrict__ Wo, const float* __restrict__ bo,
    const float* __restrict__ g_t, const float* __restrict__ b_t,
    float* __restrict__ h1)
{
  __shared__ float xs[T_][65], qs[T_][65], ks[T_][65], vs[T_][65], as_[T_][65];
  __shared__ float ps[4][T_][25];
  int tid = threadIdx.x;
  int b = blockIdx.x >> 9;
  int n = blockIdx.x & (N_-1);
  const size_t rowstride = (size_t)N_*D_;
  const float* xb = x + ((size_t)b*T_*N_ + n)*D_;
  for (int i = tid; i < T_*D_; i += 256){
    int t = i >> 6, d = i & 63;
    xs[t][d] = xb[(size_t)t*rowstride + d];
  }
  __syncthreads();
  int d = tid & 63;
  int trow = tid >> 6;            // wave id; lanes of a wave share trow
  // ---- QKV projections ----
  float aq[6], ak[6], av[6];
  {
    float bqv = bq[d], bkv = bk[d], bvv = bv[d];
#pragma unroll
    for (int i = 0; i < 6; i++){ aq[i]=bqv; ak[i]=bkv; av[i]=bvv; }
    for (int e0 = 0; e0 < 64; e0 += 16){
      float wq[16], wk[16], wv[16];
#pragma unroll
      for (int j = 0; j < 16; j++){
        wq[j] = Wq[(e0+j)*64 + d];
        wk[j] = Wk[(e0+j)*64 + d];
        wv[j] = Wv[(e0+j)*64 + d];
      }
#pragma unroll
      for (int i = 0; i < 6; i++){
        int t = trow + i*4;
#pragma unroll
        for (int j = 0; j < 16; j++){
          float xe = xs[t][e0+j];
          aq[i] = fmaf(xe, wq[j], aq[i]);
          ak[i] = fmaf(xe, wk[j], ak[i]);
          av[i] = fmaf(xe, wv[j], av[i]);
        }
      }
    }
#pragma unroll
    for (int i = 0; i < 6; i++){
      int t = trow + i*4;
      qs[t][d] = aq[i]; ks[t][d] = ak[i]; vs[t][d] = av[i];
    }
  }
  __syncthreads();
  // ---- scores ----
  for (int i = tid; i < 4*T_*T_; i += 256){
    int h = i / (T_*T_);
    int r = i - h*T_*T_;
    int t1 = r / T_, t2 = r - t1*T_;
    int hb = h*16;
    float s = 0.f;
#pragma unroll
    for (int dd = 0; dd < 16; dd++) s = fmaf(qs[t1][hb+dd], ks[t2][hb+dd], s);
    ps[h][t1][t2] = s * 0.25f;
  }
  __syncthreads();
  // ---- softmax over t2 ----
  if (tid < 96){
    int h = tid / T_, t1 = tid - (tid/T_)*T_;
    float mx = -1e30f;
#pragma unroll
    for (int j = 0; j < T_; j++) mx = fmaxf(mx, ps[h][t1][j]);
    float e[T_]; float sum = 0.f;
#pragma unroll
    for (int j = 0; j < T_; j++){ e[j] = __expf(ps[h][t1][j] - mx); sum += e[j]; }
    float inv = 1.f / sum;
#pragma unroll
    for (int j = 0; j < T_; j++) ps[h][t1][j] = e[j] * inv;
  }
  __syncthreads();
  // ---- att = attn @ v ----
  {
    int h = d >> 4;
#pragma unroll
    for (int i = 0; i < 6; i++){
      int t = trow + i*4;
      float s = 0.f;
#pragma unroll
      for (int t2 = 0; t2 < T_; t2++) s = fmaf(ps[h][t][t2], vs[t2][d], s);
      as_[t][d] = s;
    }
  }
  __syncthreads();
  // ---- Wo projection + residual ----
  float ro[6];
  {
    float bov = bo[d];
#pragma unroll
    for (int i = 0; i < 6; i++){ int t = trow + i*4; ro[i] = bov + xs[t][d]; }
    for (int e0 = 0; e0 < 64; e0 += 16){
      float wo[16];
#pragma unroll
      for (int j = 0; j < 16; j++) wo[j] = Wo[(e0+j)*64 + d];
#pragma unroll
      for (int i = 0; i < 6; i++){
        int t = trow + i*4;
#pragma unroll
        for (int j = 0; j < 16; j++) ro[i] = fmaf(as_[t][e0+j], wo[j], ro[i]);
      }
    }
  }
  // ---- LayerNorm + store ----
  float gv = g_t[d], bv2 = b_t[d];
#pragma unroll
  for (int i = 0; i < 6; i++){
    int t = trow + i*4;
    float m = wave_sum(ro[i]) * (1.f/64.f);
    float df = ro[i] - m;
    float var = wave_sum(df*df) * (1.f/64.f);
    float y = df * rsqrtf(var + 1e-5f) * gv + bv2;
    h1[((size_t)(b*T_ + t)*N_ + n)*D_ + d] = y;
  }
}

// ---------- Y = Ahat @ X (per bt-slice) with fused epilogue G += Y @ gcWk ----------
// TX = float (hop 1: X = h1 in d_out) or bf16 (hop 2: X = p in ws).
template<typename TX>
__global__ __launch_bounds__(256) void k_prop_g(
    const float* __restrict__ Ahat,
    const TX* __restrict__ X,         // [BT][N][D]
    const float* __restrict__ gcWk,   // [64][64]
    bf16* __restrict__ P,             // propagated output (written iff store_p)
    bf16* __restrict__ G,             // g12 accumulator [BT*N][D]
    int store_p, int accum)
{
  __shared__ float At[32][68];   // A-tile transposed; stride 68 keeps 16B align
  __shared__ float Xs[32][64];
  __shared__ float YsT[64][68];  // Y tile transposed (e-major) for epilogue
  __shared__ float Ws[64][68];   // gcWk staged
  int tid = threadIdx.x;
  int tx = tid & 15, ty = tid >> 4;
  int m0 = blockIdx.x * 64;
  size_t slice = (size_t)blockIdx.y * (N_*D_);
  const TX* Xg = X + slice;
  float acc[4][4] = {};
  for (int k0 = 0; k0 < N_; k0 += 32){
#pragma unroll
    for (int i = 0; i < 8; i++){
      int idx = tid + i*256;
      int kk = idx & 31, m = idx >> 5;           // coalesced global read
      At[kk][m] = Ahat[(size_t)(m0+m)*N_ + k0 + kk];
    }
#pragma unroll
    for (int i = 0; i < 8; i++){
      int idx = tid + i*256;
      int dd = idx & 63, kk = idx >> 6;
      Xs[kk][dd] = toF(Xg[(size_t)(k0+kk)*D_ + dd]);
    }
    __syncthreads();
#pragma unroll
    for (int kk = 0; kk < 32; kk++){
      float4 a  = *(const float4*)&At[kk][ty*4];
      float4 xv = *(const float4*)&Xs[kk][tx*4];
      float aa[4] = {a.x,a.y,a.z,a.w};
      float xx[4] = {xv.x,xv.y,xv.z,xv.w};
#pragma unroll
      for (int i = 0; i < 4; i++)
#pragma unroll
        for (int j = 0; j < 4; j++)
          acc[i][j] = fmaf(aa[i], xx[j], acc[i][j]);
    }
    __syncthreads();
  }
  // stage gcWk and the Y tile (transposed) into LDS
  for (int i = tid; i < 64*64; i += 256){
    int e = i >> 6, dd = i & 63;
    Ws[e][dd] = gcWk[i];
  }
#pragma unroll
  for (int i = 0; i < 4; i++)
#pragma unroll
    for (int j = 0; j < 4; j++)
      YsT[tx*4 + j][ty*4 + i] = acc[i][j];
  // optionally store propagated tensor (bf16)
  if (store_p){
#pragma unroll
    for (int i = 0; i < 4; i++){
      int m = m0 + ty*4 + i;
      __align__(8) bf16 tmp[4];
#pragma unroll
      for (int j = 0; j < 4; j++) tmp[j] = f2b(acc[i][j]);
      *(uint2*)&P[slice + (size_t)m*D_ + tx*4] = *(uint2*)tmp;
    }
  }
  __syncthreads();
  // epilogue GEMM: gtile[t][d] = sum_e Y[t][e] * Ws[e][d]
  float acc2[4][4] = {};
#pragma unroll
  for (int kk = 0; kk < 64; kk++){
    float4 a = *(const float4*)&YsT[kk][ty*4];
    float4 w = *(const float4*)&Ws[kk][tx*4];
    float aa[4] = {a.x,a.y,a.z,a.w};
    float ww[4] = {w.x,w.y,w.z,w.w};
#pragma unroll
    for (int i = 0; i < 4; i++)
#pragma unroll
      for (int j = 0; j < 4; j++)
        acc2[i][j] = fmaf(aa[i], ww[j], acc2[i][j]);
  }
#pragma unroll
  for (int i = 0; i < 4; i++){
    int m = m0 + ty*4 + i;
    size_t base = slice + (size_t)m*D_ + tx*4;
    __align__(8) bf16 tmp[4];
    if (accum){
      __align__(8) bf16 oldv[4];
      *(uint2*)oldv = *(const uint2*)&G[base];
#pragma unroll
      for (int j = 0; j < 4; j++) tmp[j] = f2b(acc2[i][j] + b2f(oldv[j]));
    } else {
#pragma unroll
      for (int j = 0; j < 4; j++) tmp[j] = f2b(acc2[i][j]);
    }
    *(uint2*)&G[base] = *(uint2*)tmp;
  }
}

// ---------- h2 = LN(h1 + h1@gcW0 + g12 + sum(gcb)) ; in-place on d_out ----------
__global__ __launch_bounds__(256) void k_comb(
  const bf16* __restrict__ g12,
  const float* __restrict__ gcW, const float* __restrict__ gcb,
  const float* __restrict__ g_g, const float* __restrict__ b_g,
  float* __restrict__ h)          // h1 in, h2 out (same buffer)
{
  __shared__ float hs[32][64];
  int tid = threadIdx.x;
  size_t tok0 = (size_t)blockIdx.x * 32;
#pragma unroll
  for (int i = 0; i < 8; i++){
    int idx = tid + i*256;
    int dd = idx & 63, t = idx >> 6;
    hs[t][dd] = h[(tok0 + t)*64 + dd];
  }
  __syncthreads();
  int d = tid & 63, trow = tid >> 6;
  float acc[8];
  float bsum = gcb[d] + gcb[64+d] + gcb[128+d];
#pragma unroll
  for (int i = 0; i < 8; i++) acc[i] = bsum + b2f(g12[(tok0 + trow + i*4)*64 + d]);
  for (int e0 = 0; e0 < 64; e0 += 16){
    float w0[16];
#pragma unroll
    for (int j = 0; j < 16; j++) w0[j] = gcW[(e0+j)*64 + d];
#pragma unroll
    for (int i = 0; i < 8; i++){
      int t = trow + i*4;
#pragma unroll
      for (int j = 0; j < 16; j++) acc[i] = fmaf(hs[t][e0+j], w0[j], acc[i]);
    }
  }
  float gv = g_g[d], bv = b_g[d];
#pragma unroll
  for (int i = 0; i < 8; i++){
    int t = trow + i*4;
    float v = acc[i] + hs[t][d];
    float m = wave_sum(v) * (1.f/64.f);
    float df = v - m;
    float var = wave_sum(df*df) * (1.f/64.f);
    float y = df * rsqrtf(var + 1e-5f) * gv + bv;
    h[(tok0 + t)*64 + d] = y;
  }
}

// ---------- FFN (64->256 gelu ->64) + residual + LN ; in-place on d_out ----------
__global__ __launch_bounds__(256) void k_ffn(
  const float* __restrict__ W1, const float* __restrict__ b1,
  const float* __restrict__ W2, const float* __restrict__ b2,
  const float* __restrict__ g_f, const float* __restrict__ b_f,
  float* __restrict__ h)          // h2 in, out out (same buffer)
{
  __shared__ float hs[16][64];
  __shared__ float us[16][256];
  int tid = threadIdx.x;
  size_t tok0 = (size_t)blockIdx.x * 16;
#pragma unroll
  for (int i = 0; i < 4; i++){
    int idx = tid + i*256;
    int dd = idx & 63, t = idx >> 6;
    hs[t][dd] = h[(tok0 + t)*64 + dd];
  }
  __syncthreads();
  // phase 1: hidden column j = tid for all 16 tokens
  {
    float acc[16];
    float bb = b1[tid];
#pragma unroll
    for (int t = 0; t < 16; t++) acc[t] = bb;
    for (int e0 = 0; e0 < 64; e0 += 16){
      float w[16];
#pragma unroll
      for (int j = 0; j < 16; j++) w[j] = W1[(e0+j)*256 + tid];
#pragma unroll
      for (int t = 0; t < 16; t++){
#pragma unroll
        for (int j = 0; j < 16; j++)
          acc[t] = fmaf(hs[t][e0+j], w[j], acc[t]);
      }
    }
#pragma unroll
    for (int t = 0; t < 16; t++){
      float u = acc[t];
      us[t][tid] = 0.5f * u * (1.f + erff(u * 0.70710678118654752f)); // exact GELU
    }
  }
  __syncthreads();
  // phase 2: back to D=64
  int d = tid & 63, trow = tid >> 6;
  float o[4];
  float b2v = b2[d];
#pragma unroll
  for (int i = 0; i < 4; i++) o[i] = b2v;
  for (int j0 = 0; j0 < 256; j0 += 16){
    float w[16];
#pragma unroll
    for (int j = 0; j < 16; j++) w[j] = W2[(j0+j)*64 + d];
#pragma unroll
    for (int i = 0; i < 4; i++){
      int t = trow + i*4;
#pragma unroll
      for (int j = 0; j < 16; j++)
        o[i] = fmaf(us[t][j0+j], w[j], o[i]);
    }
  }
  float gv = g_f[d], bv = b_f[d];
#pragma unroll
  for (int i = 0; i < 4; i++){
    int t = trow + i*4;
    float v = o[i] + hs[t][d];
    float m = wave_sum(v) * (1.f/64.f);
    float df = v - m;
    float var = wave_sum(df*df) * (1.f/64.f);
    float y = df * rsqrtf(var + 1e-5f) * gv + bv;
    h[(tok0 + t)*64 + d] = y;
  }
}

extern "C" void kernel_launch(void* const* d_in, const int* in_sizes, int n_in,
                              void* d_out, int out_size, void* d_ws, size_t ws_size,
                              hipStream_t stream)
{
  const float* x   = (const float*)d_in[0];
  const float* adj = (const float*)d_in[1];
  const float* Wq  = (const float*)d_in[2];
  const float* bq  = (const float*)d_in[3];
  const float* Wk  = (const float*)d_in[4];
  const float* bk  = (const float*)d_in[5];
  const float* Wv  = (const float*)d_in[6];
  const float* bv  = (const float*)d_in[7];
  const float* Wo  = (const float*)d_in[8];
  const float* bo  = (const float*)d_in[9];
  const float* gcW = (const float*)d_in[10];
  const float* gcb = (const float*)d_in[11];
  const float* W1  = (const float*)d_in[12];
  const float* b1  = (const float*)d_in[13];
  const float* W2  = (const float*)d_in[14];
  const float* b2  = (const float*)d_in[15];
  const float* g_t = (const float*)d_in[16];
  const float* b_t = (const float*)d_in[17];
  const float* g_g = (const float*)d_in[18];
  const float* b_g = (const float*)d_in[19];
  const float* g_f = (const float*)d_in[20];
  const float* b_f = (const float*)d_in[21];

  // workspace (~51.4 MB): dinv(2KB) | Ahat f32 (1MB) | p bf16 (25.2MB) | g12 bf16 (25.2MB)
  const size_t MD = (size_t)B_*T_*N_*D_;
  float* dinv = (float*)d_ws;
  float* Ahat = dinv + 512;
  bf16* p   = (bf16*)(Ahat + (size_t)N_*N_);
  bf16* g12 = p + MD;
  float* h  = (float*)d_out;     // h1 -> h2 -> out, all staged in d_out (fp32)

  k_dinv<<<N_, 64, 0, stream>>>(adj, dinv);
  k_ahat<<<(N_*N_)/256, 256, 0, stream>>>(adj, dinv, Ahat);
  k_attn<<<B_*N_, 256, 0, stream>>>(x, Wq,bq, Wk,bk, Wv,bv, Wo,bo, g_t,b_t, h);
  // hop 1: p = Ahat@h1 ; g12 = p@gcW1   (fp32 Y used for the projection)
  k_prop_g<float><<<dim3(N_/64, B_*T_), 256, 0, stream>>>(Ahat, h, gcW + 4096, p, g12, 1, 0);
  // hop 2: Y = Ahat@p (not stored) ; g12 += Y@gcW2
  k_prop_g<bf16><<<dim3(N_/64, B_*T_), 256, 0, stream>>>(Ahat, p, gcW + 8192, p, g12, 0, 1);
  k_comb<<<(int)(MD/D_/32), 256, 0, stream>>>(g12, gcW, gcb, g_g, b_g, h);
  k_ffn<<<(int)(MD/D_/16), 256, 0, stream>>>(W1,b1, W2,b2, g_f,b_f, h);
}

// Round 4
// 936.865 us; speedup vs baseline: 1.8031x; 1.8031x over previous
//
#include <hip/hip_runtime.h>
#include <hip/hip_bf16.h>
#include <math.h>

typedef __hip_bfloat16 bf16;
typedef unsigned short ushort_t;

__device__ __forceinline__ float us2f(ushort_t u){
  union { unsigned u; float f; } v; v.u = ((unsigned)u) << 16; return v.f;
}
__device__ __forceinline__ ushort_t f2us(float f){
  union { float f; unsigned u; } v; v.f = f;
  unsigned r = v.u + 0x7fff + ((v.u >> 16) & 1);   // RNE
  return (ushort_t)(r >> 16);
}
__device__ __forceinline__ float ldX(float v){ return v; }
__device__ __forceinline__ float ldX(ushort_t v){ return us2f(v); }

#define B_ 16
#define T_ 24
#define N_ 512
#define D_ 64
#define F_ 256

typedef __attribute__((ext_vector_type(8)))  short  frag8;
typedef __attribute__((ext_vector_type(16))) float  accv16;

__device__ __forceinline__ float wave_sum(float v){
#pragma unroll
  for (int off = 32; off > 0; off >>= 1) v += __shfl_xor(v, off, 64);
  return v;
}

// ---------- degree^-1/2 ----------
__global__ __launch_bounds__(64) void k_dinv(const float* __restrict__ adj,
                                             float* __restrict__ dinv){
  int m = blockIdx.x;
  float s = 0.f;
  for (int n = threadIdx.x; n < N_; n += 64) s += adj[m*N_ + n];
  s = wave_sum(s);
  if (threadIdx.x == 0){
    float deg = s + 1.0f;
    dinv[m] = rsqrtf(fmaxf(deg, 1e-12f));
  }
}

// ---------- Ahat (bf16) = dinv_m * (adj + I) * dinv_n ----------
__global__ __launch_bounds__(256) void k_ahat(const float* __restrict__ adj,
                                              const float* __restrict__ dinv,
                                              ushort_t* __restrict__ AhatB){
  int idx = blockIdx.x*256 + threadIdx.x;
  int m = idx >> 9, n = idx & (N_-1);
  float a = adj[idx] + (m == n ? 1.f : 0.f);
  AhatB[idx] = f2us(dinv[m]*a*dinv[n]);
}

// ---------- fused temporal attention + Wo + residual + LN -> h1 (in d_out) ----------
__global__ __launch_bounds__(256) void k_attn(
    const float* __restrict__ x,
    const float* __restrict__ Wq, const float* __restrict__ bq,
    const float* __restrict__ Wk, const float* __restrict__ bk,
    const float* __restrict__ Wv, const float* __restrict__ bv,
    const float* __restrict__ Wo, const float* __restrict__ bo,
    const float* __restrict__ g_t, const float* __restrict__ b_t,
    float* __restrict__ h1)
{
  __shared__ float xs[T_][65], qs[T_][65], ks[T_][65], vs[T_][65], as_[T_][65];
  __shared__ float ps[4][T_][25];
  int tid = threadIdx.x;
  int b = blockIdx.x >> 9;
  int n = blockIdx.x & (N_-1);
  const size_t rowstride = (size_t)N_*D_;
  const float* xb = x + ((size_t)b*T_*N_ + n)*D_;
  for (int i = tid; i < T_*D_; i += 256){
    int t = i >> 6, d = i & 63;
    xs[t][d] = xb[(size_t)t*rowstride + d];
  }
  __syncthreads();
  int d = tid & 63;
  int trow = tid >> 6;
  float aq[6], ak[6], av[6];
  {
    float bqv = bq[d], bkv = bk[d], bvv = bv[d];
#pragma unroll
    for (int i = 0; i < 6; i++){ aq[i]=bqv; ak[i]=bkv; av[i]=bvv; }
    for (int e0 = 0; e0 < 64; e0 += 16){
      float wq[16], wk[16], wv[16];
#pragma unroll
      for (int j = 0; j < 16; j++){
        wq[j] = Wq[(e0+j)*64 + d];
        wk[j] = Wk[(e0+j)*64 + d];
        wv[j] = Wv[(e0+j)*64 + d];
      }
#pragma unroll
      for (int i = 0; i < 6; i++){
        int t = trow + i*4;
#pragma unroll
        for (int j = 0; j < 16; j++){
          float xe = xs[t][e0+j];
          aq[i] = fmaf(xe, wq[j], aq[i]);
          ak[i] = fmaf(xe, wk[j], ak[i]);
          av[i] = fmaf(xe, wv[j], av[i]);
        }
      }
    }
#pragma unroll
    for (int i = 0; i < 6; i++){
      int t = trow + i*4;
      qs[t][d] = aq[i]; ks[t][d] = ak[i]; vs[t][d] = av[i];
    }
  }
  __syncthreads();
  for (int i = tid; i < 4*T_*T_; i += 256){
    int h = i / (T_*T_);
    int r = i - h*T_*T_;
    int t1 = r / T_, t2 = r - t1*T_;
    int hb = h*16;
    float s = 0.f;
#pragma unroll
    for (int dd = 0; dd < 16; dd++) s = fmaf(qs[t1][hb+dd], ks[t2][hb+dd], s);
    ps[h][t1][t2] = s * 0.25f;
  }
  __syncthreads();
  if (tid < 96){
    int h = tid / T_, t1 = tid - (tid/T_)*T_;
    float mx = -1e30f;
#pragma unroll
    for (int j = 0; j < T_; j++) mx = fmaxf(mx, ps[h][t1][j]);
    float e[T_]; float sum = 0.f;
#pragma unroll
    for (int j = 0; j < T_; j++){ e[j] = __expf(ps[h][t1][j] - mx); sum += e[j]; }
    float inv = 1.f / sum;
#pragma unroll
    for (int j = 0; j < T_; j++) ps[h][t1][j] = e[j] * inv;
  }
  __syncthreads();
  {
    int h = d >> 4;
#pragma unroll
    for (int i = 0; i < 6; i++){
      int t = trow + i*4;
      float s = 0.f;
#pragma unroll
      for (int t2 = 0; t2 < T_; t2++) s = fmaf(ps[h][t][t2], vs[t2][d], s);
      as_[t][d] = s;
    }
  }
  __syncthreads();
  float ro[6];
  {
    float bov = bo[d];
#pragma unroll
    for (int i = 0; i < 6; i++){ int t = trow + i*4; ro[i] = bov + xs[t][d]; }
    for (int e0 = 0; e0 < 64; e0 += 16){
      float wo[16];
#pragma unroll
      for (int j = 0; j < 16; j++) wo[j] = Wo[(e0+j)*64 + d];
#pragma unroll
      for (int i = 0; i < 6; i++){
        int t = trow + i*4;
#pragma unroll
        for (int j = 0; j < 16; j++) ro[i] = fmaf(as_[t][e0+j], wo[j], ro[i]);
      }
    }
  }
  float gv = g_t[d], bv2 = b_t[d];
#pragma unroll
  for (int i = 0; i < 6; i++){
    int t = trow + i*4;
    float m = wave_sum(ro[i]) * (1.f/64.f);
    float df = ro[i] - m;
    float var = wave_sum(df*df) * (1.f/64.f);
    float y = df * rsqrtf(var + 1e-5f) * gv + bv2;
    h1[((size_t)(b*T_ + t)*N_ + n)*D_ + d] = y;
  }
}

// ---------- MFMA prop: Y = Ahat@X (per slice), fused G (+)= Y@gcWk ----------
// 4 waves, 64x64 output tile (2x2 of 32x32 MFMA tiles), K=512 in BK=64 chunks.
// A-operand (Ahat) LDS: [m][k] k-contig; B-operand (X) LDS transposed [n][k].
template<typename TX>
__global__ __launch_bounds__(256, 4) void k_prop_m(
    const ushort_t* __restrict__ Ahat,  // [512][512] bf16
    const TX* __restrict__ X,           // [BT][512][64]
    const float* __restrict__ gcWk,     // [64][64] fp32, row-major [e][d]
    ushort_t* __restrict__ P,
    ushort_t* __restrict__ G,
    int store_p, int accum)
{
  __shared__ __align__(16) ushort_t Ab[64][72];  // stride 144B: 16B-aligned, 4-way bank alias (ok)
  __shared__ __align__(16) ushort_t Xb[64][72];  // X transposed: Xb[n][k]
  __shared__ __align__(16) ushort_t Yt[64][72];  // Y tile bf16, [m][e]
  __shared__ __align__(16) ushort_t Wt[64][72];  // gcWk transposed: Wt[d][e]
  int tid  = threadIdx.x;
  int lane = tid & 63, w = tid >> 6;
  int mw = (w >> 1) * 32, nw = (w & 1) * 32;
  int l31 = lane & 31, lh = lane >> 5;
  int m0 = blockIdx.x * 64;
  size_t slice = (size_t)blockIdx.y * (N_ * D_);
  const TX* Xg = X + slice;

  // stage Wt[d][e] = gcWk[e][d] (coalesced over d; b128 LDS writes)
  {
    int d = tid & 63, e4 = tid >> 6;
#pragma unroll
    for (int g = 0; g < 2; g++){
      int es = (e4 + g*4) * 8;
      ushort_t tmp[8];
#pragma unroll
      for (int i = 0; i < 8; i++) tmp[i] = f2us(gcWk[(es + i)*64 + d]);
      *(uint4*)&Wt[d][es] = *(uint4*)tmp;
    }
  }

  accv16 acc = {};
  int ar = tid >> 3, ac8 = (tid & 7) * 8;        // A-stage coords
  int xn = tid & 63, xk4 = tid >> 6;             // X-stage coords
  for (int k0 = 0; k0 < N_; k0 += 64){
    // A-tile: rows m0..m0+63, cols k0..k0+63 (b128 global + b128 LDS)
#pragma unroll
    for (int g = 0; g < 2; g++){
      int rr = ar + g*32;
      *(uint4*)&Ab[rr][ac8] =
        *(const uint4*)&Ahat[(size_t)(m0 + rr)*N_ + k0 + ac8];
    }
    // X-tile transposed: Xb[n][k] (coalesced column-segment reads)
#pragma unroll
    for (int g = 0; g < 2; g++){
      int ks = (xk4 + g*4) * 8;
      ushort_t tmp[8];
#pragma unroll
      for (int i = 0; i < 8; i++) tmp[i] = f2us(ldX(Xg[(size_t)(k0 + ks + i)*D_ + xn]));
      *(uint4*)&Xb[xn][ks] = *(uint4*)tmp;
    }
    __syncthreads();
#pragma unroll
    for (int kk = 0; kk < 64; kk += 16){
      frag8 af = *(const frag8*)&Ab[mw + l31][kk + lh*8];
      frag8 bf = *(const frag8*)&Xb[nw + l31][kk + lh*8];
      acc = __builtin_amdgcn_mfma_f32_32x32x16_bf16(af, bf, acc, 0, 0, 0);
    }
    __syncthreads();
  }

  // acc (C/D layout: col=lane&31, row=(reg&3)+8*(reg>>2)+4*(lane>>5)) -> Yt bf16
#pragma unroll
  for (int r = 0; r < 16; r++){
    int row = mw + (r & 3) + 8*(r >> 2) + 4*lh;
    Yt[row][nw + l31] = f2us(acc[r]);
  }
  __syncthreads();

  if (store_p){
#pragma unroll
    for (int g = 0; g < 2; g++){
      int rr = ar + g*32;
      *(uint4*)&P[slice + (size_t)(m0 + rr)*D_ + ac8] = *(const uint4*)&Yt[rr][ac8];
    }
  }

  // epilogue MFMA: Gt[m][d] = sum_e Y[m][e] * W[e][d]
  accv16 acc2 = {};
#pragma unroll
  for (int kk = 0; kk < 64; kk += 16){
    frag8 af = *(const frag8*)&Yt[mw + l31][kk + lh*8];
    frag8 bf = *(const frag8*)&Wt[nw + l31][kk + lh*8];
    acc2 = __builtin_amdgcn_mfma_f32_32x32x16_bf16(af, bf, acc2, 0, 0, 0);
  }
  // reuse Ab as Gt staging
#pragma unroll
  for (int r = 0; r < 16; r++){
    int row = mw + (r & 3) + 8*(r >> 2) + 4*lh;
    Ab[row][nw + l31] = f2us(acc2[r]);
  }
  __syncthreads();
#pragma unroll
  for (int g = 0; g < 2; g++){
    int rr = ar + g*32;
    uint4 vv = *(const uint4*)&Ab[rr][ac8];
    size_t base = slice + (size_t)(m0 + rr)*D_ + ac8;
    if (accum){
      uint4 ov = *(const uint4*)&G[base];
      ushort_t* s = (ushort_t*)&vv;
      ushort_t* o = (ushort_t*)&ov;
      ushort_t res[8];
#pragma unroll
      for (int i = 0; i < 8; i++) res[i] = f2us(us2f(s[i]) + us2f(o[i]));
      *(uint4*)&G[base] = *(uint4*)res;
    } else {
      *(uint4*)&G[base] = vv;
    }
  }
}

// ---------- h2 = LN(h1 + h1@gcW0 + g12 + sum(gcb)) ; in-place on d_out ----------
__global__ __launch_bounds__(256) void k_comb(
  const ushort_t* __restrict__ g12,
  const float* __restrict__ gcW, const float* __restrict__ gcb,
  const float* __restrict__ g_g, const float* __restrict__ b_g,
  float* __restrict__ h)
{
  __shared__ float hs[32][64];
  int tid = threadIdx.x;
  size_t tok0 = (size_t)blockIdx.x * 32;
#pragma unroll
  for (int i = 0; i < 8; i++){
    int idx = tid + i*256;
    int dd = idx & 63, t = idx >> 6;
    hs[t][dd] = h[(tok0 + t)*64 + dd];
  }
  __syncthreads();
  int d = tid & 63, trow = tid >> 6;
  float acc[8];
  float bsum = gcb[d] + gcb[64+d] + gcb[128+d];
#pragma unroll
  for (int i = 0; i < 8; i++) acc[i] = bsum + us2f(g12[(tok0 + trow + i*4)*64 + d]);
  for (int e0 = 0; e0 < 64; e0 += 16){
    float w0[16];
#pragma unroll
    for (int j = 0; j < 16; j++) w0[j] = gcW[(e0+j)*64 + d];
#pragma unroll
    for (int i = 0; i < 8; i++){
      int t = trow + i*4;
#pragma unroll
      for (int j = 0; j < 16; j++) acc[i] = fmaf(hs[t][e0+j], w0[j], acc[i]);
    }
  }
  float gv = g_g[d], bv = b_g[d];
#pragma unroll
  for (int i = 0; i < 8; i++){
    int t = trow + i*4;
    float v = acc[i] + hs[t][d];
    float m = wave_sum(v) * (1.f/64.f);
    float df = v - m;
    float var = wave_sum(df*df) * (1.f/64.f);
    float y = df * rsqrtf(var + 1e-5f) * gv + bv;
    h[(tok0 + t)*64 + d] = y;
  }
}

// ---------- FFN (64->256 gelu ->64) + residual + LN ; in-place on d_out ----------
__global__ __launch_bounds__(256) void k_ffn(
  const float* __restrict__ W1, const float* __restrict__ b1,
  const float* __restrict__ W2, const float* __restrict__ b2,
  const float* __restrict__ g_f, const float* __restrict__ b_f,
  float* __restrict__ h)
{
  __shared__ float hs[16][64];
  __shared__ float us[16][256];
  int tid = threadIdx.x;
  size_t tok0 = (size_t)blockIdx.x * 16;
#pragma unroll
  for (int i = 0; i < 4; i++){
    int idx = tid + i*256;
    int dd = idx & 63, t = idx >> 6;
    hs[t][dd] = h[(tok0 + t)*64 + dd];
  }
  __syncthreads();
  {
    float acc[16];
    float bb = b1[tid];
#pragma unroll
    for (int t = 0; t < 16; t++) acc[t] = bb;
    for (int e0 = 0; e0 < 64; e0 += 16){
      float w[16];
#pragma unroll
      for (int j = 0; j < 16; j++) w[j] = W1[(e0+j)*256 + tid];
#pragma unroll
      for (int t = 0; t < 16; t++){
#pragma unroll
        for (int j = 0; j < 16; j++)
          acc[t] = fmaf(hs[t][e0+j], w[j], acc[t]);
      }
    }
#pragma unroll
    for (int t = 0; t < 16; t++){
      float u = acc[t];
      us[t][tid] = 0.5f * u * (1.f + erff(u * 0.70710678118654752f));
    }
  }
  __syncthreads();
  int d = tid & 63, trow = tid >> 6;
  float o[4];
  float b2v = b2[d];
#pragma unroll
  for (int i = 0; i < 4; i++) o[i] = b2v;
  for (int j0 = 0; j0 < 256; j0 += 16){
    float w[16];
#pragma unroll
    for (int j = 0; j < 16; j++) w[j] = W2[(j0+j)*64 + d];
#pragma unroll
    for (int i = 0; i < 4; i++){
      int t = trow + i*4;
#pragma unroll
      for (int j = 0; j < 16; j++)
        o[i] = fmaf(us[t][j0+j], w[j], o[i]);
    }
  }
  float gv = g_f[d], bv = b_f[d];
#pragma unroll
  for (int i = 0; i < 4; i++){
    int t = trow + i*4;
    float v = o[i] + hs[t][d];
    float m = wave_sum(v) * (1.f/64.f);
    float df = v - m;
    float var = wave_sum(df*df) * (1.f/64.f);
    float y = df * rsqrtf(var + 1e-5f) * gv + bv;
    h[(tok0 + t)*64 + d] = y;
  }
}

extern "C" void kernel_launch(void* const* d_in, const int* in_sizes, int n_in,
                              void* d_out, int out_size, void* d_ws, size_t ws_size,
                              hipStream_t stream)
{
  const float* x   = (const float*)d_in[0];
  const float* adj = (const float*)d_in[1];
  const float* Wq  = (const float*)d_in[2];
  const float* bq  = (const float*)d_in[3];
  const float* Wk  = (const float*)d_in[4];
  const float* bk  = (const float*)d_in[5];
  const float* Wv  = (const float*)d_in[6];
  const float* bv  = (const float*)d_in[7];
  const float* Wo  = (const float*)d_in[8];
  const float* bo  = (const float*)d_in[9];
  const float* gcW = (const float*)d_in[10];
  const float* gcb = (const float*)d_in[11];
  const float* W1  = (const float*)d_in[12];
  const float* b1  = (const float*)d_in[13];
  const float* W2  = (const float*)d_in[14];
  const float* b2  = (const float*)d_in[15];
  const float* g_t = (const float*)d_in[16];
  const float* b_t = (const float*)d_in[17];
  const float* g_g = (const float*)d_in[18];
  const float* b_g = (const float*)d_in[19];
  const float* g_f = (const float*)d_in[20];
  const float* b_f = (const float*)d_in[21];

  // ws (~50.9 MB): dinv 2KB | Ahat bf16 512KB | p bf16 25.2MB | g12 bf16 25.2MB
  const size_t MD = (size_t)B_*T_*N_*D_;
  float* dinv = (float*)d_ws;
  ushort_t* AhatB = (ushort_t*)(dinv + 512);
  ushort_t* p   = AhatB + (size_t)N_*N_;
  ushort_t* g12 = p + MD;
  float* h = (float*)d_out;     // h1 -> h2 -> out, staged fp32 in d_out

  k_dinv<<<N_, 64, 0, stream>>>(adj, dinv);
  k_ahat<<<(N_*N_)/256, 256, 0, stream>>>(adj, dinv, AhatB);
  k_attn<<<B_*N_, 256, 0, stream>>>(x, Wq,bq, Wk,bk, Wv,bv, Wo,bo, g_t,b_t, h);
  // hop 1: p = Ahat@h1 ; g12 = p@gcW1
  k_prop_m<float><<<dim3(N_/64, B_*T_), 256, 0, stream>>>(AhatB, h, gcW + 4096, p, g12, 1, 0);
  // hop 2: Y = Ahat@p (not stored) ; g12 += Y@gcW2
  k_prop_m<ushort_t><<<dim3(N_/64, B_*T_), 256, 0, stream>>>(AhatB, p, gcW + 8192, p, g12, 0, 1);
  k_comb<<<(int)(MD/D_/32), 256, 0, stream>>>(g12, gcW, gcb, g_g, b_g, h);
  k_ffn<<<(int)(MD/D_/16), 256, 0, stream>>>(W1,b1, W2,b2, g_f,b_f, h);
}

// Round 5
// 625.272 us; speedup vs baseline: 2.7016x; 1.4983x over previous
//
#include <hip/hip_runtime.h>
#include <hip/hip_bf16.h>
#include <math.h>

typedef __hip_bfloat16 bf16;
typedef unsigned short ushort_t;

__device__ __forceinline__ float us2f(ushort_t u){
  union { unsigned u; float f; } v; v.u = ((unsigned)u) << 16; return v.f;
}
__device__ __forceinline__ ushort_t f2us(float f){
  union { float f; unsigned u; } v; v.f = f;
  unsigned r = v.u + 0x7fff + ((v.u >> 16) & 1);   // RNE
  return (ushort_t)(r >> 16);
}
__device__ __forceinline__ float ldX(float v){ return v; }
__device__ __forceinline__ float ldX(ushort_t v){ return us2f(v); }

#define B_ 16
#define T_ 24
#define N_ 512
#define D_ 64
#define F_ 256

typedef __attribute__((ext_vector_type(8)))  short  frag8;
typedef __attribute__((ext_vector_type(16))) float  accv16;

__device__ __forceinline__ float wave_sum(float v){
#pragma unroll
  for (int off = 32; off > 0; off >>= 1) v += __shfl_xor(v, off, 64);
  return v;
}

// ---------- degree^-1/2 ----------
__global__ __launch_bounds__(64) void k_dinv(const float* __restrict__ adj,
                                             float* __restrict__ dinv){
  int m = blockIdx.x;
  float s = 0.f;
  for (int n = threadIdx.x; n < N_; n += 64) s += adj[m*N_ + n];
  s = wave_sum(s);
  if (threadIdx.x == 0){
    float deg = s + 1.0f;
    dinv[m] = rsqrtf(fmaxf(deg, 1e-12f));
  }
}

// ---------- Ahat (bf16) = dinv_m * (adj + I) * dinv_n ----------
__global__ __launch_bounds__(256) void k_ahat(const float* __restrict__ adj,
                                              const float* __restrict__ dinv,
                                              ushort_t* __restrict__ AhatB){
  int idx = blockIdx.x*256 + threadIdx.x;
  int m = idx >> 9, n = idx & (N_-1);
  float a = adj[idx] + (m == n ? 1.f : 0.f);
  AhatB[idx] = f2us(dinv[m]*a*dinv[n]);
}

// ---------- pre-transpose FFN weights to bf16 B-operand layout ----------
// W1t[f][e] (256x64), W2t[d][e] (64x256)
__global__ __launch_bounds__(256) void k_wprep(const float* __restrict__ W1,
                                               const float* __restrict__ W2,
                                               ushort_t* __restrict__ W1t,
                                               ushort_t* __restrict__ W2t){
  int o = blockIdx.x*256 + threadIdx.x;   // 0..16383
  int f = o >> 6, e = o & 63;
  W1t[o] = f2us(W1[e*256 + f]);
  int d = o >> 8, e2 = o & 255;
  W2t[o] = f2us(W2[e2*64 + d]);
}

// ---------- fused temporal attention + Wo + residual + LN -> h1 (in d_out) ----------
__global__ __launch_bounds__(256) void k_attn(
    const float* __restrict__ x,
    const float* __restrict__ Wq, const float* __restrict__ bq,
    const float* __restrict__ Wk, const float* __restrict__ bk,
    const float* __restrict__ Wv, const float* __restrict__ bv,
    const float* __restrict__ Wo, const float* __restrict__ bo,
    const float* __restrict__ g_t, const float* __restrict__ b_t,
    float* __restrict__ h1)
{
  __shared__ float xs[T_][65], qs[T_][65], ks[T_][65], vs[T_][65], as_[T_][65];
  __shared__ float ps[4][T_][25];
  int tid = threadIdx.x;
  int b = blockIdx.x >> 9;
  int n = blockIdx.x & (N_-1);
  const size_t rowstride = (size_t)N_*D_;
  const float* xb = x + ((size_t)b*T_*N_ + n)*D_;
  for (int i = tid; i < T_*D_; i += 256){
    int t = i >> 6, d = i & 63;
    xs[t][d] = xb[(size_t)t*rowstride + d];
  }
  __syncthreads();
  int d = tid & 63;
  int trow = tid >> 6;
  float aq[6], ak[6], av[6];
  {
    float bqv = bq[d], bkv = bk[d], bvv = bv[d];
#pragma unroll
    for (int i = 0; i < 6; i++){ aq[i]=bqv; ak[i]=bkv; av[i]=bvv; }
    for (int e0 = 0; e0 < 64; e0 += 16){
      float wq[16], wk[16], wv[16];
#pragma unroll
      for (int j = 0; j < 16; j++){
        wq[j] = Wq[(e0+j)*64 + d];
        wk[j] = Wk[(e0+j)*64 + d];
        wv[j] = Wv[(e0+j)*64 + d];
      }
#pragma unroll
      for (int i = 0; i < 6; i++){
        int t = trow + i*4;
#pragma unroll
        for (int j = 0; j < 16; j++){
          float xe = xs[t][e0+j];
          aq[i] = fmaf(xe, wq[j], aq[i]);
          ak[i] = fmaf(xe, wk[j], ak[i]);
          av[i] = fmaf(xe, wv[j], av[i]);
        }
      }
    }
#pragma unroll
    for (int i = 0; i < 6; i++){
      int t = trow + i*4;
      qs[t][d] = aq[i]; ks[t][d] = ak[i]; vs[t][d] = av[i];
    }
  }
  __syncthreads();
  for (int i = tid; i < 4*T_*T_; i += 256){
    int h = i / (T_*T_);
    int r = i - h*T_*T_;
    int t1 = r / T_, t2 = r - t1*T_;
    int hb = h*16;
    float s = 0.f;
#pragma unroll
    for (int dd = 0; dd < 16; dd++) s = fmaf(qs[t1][hb+dd], ks[t2][hb+dd], s);
    ps[h][t1][t2] = s * 0.25f;
  }
  __syncthreads();
  if (tid < 96){
    int h = tid / T_, t1 = tid - (tid/T_)*T_;
    float mx = -1e30f;
#pragma unroll
    for (int j = 0; j < T_; j++) mx = fmaxf(mx, ps[h][t1][j]);
    float e[T_]; float sum = 0.f;
#pragma unroll
    for (int j = 0; j < T_; j++){ e[j] = __expf(ps[h][t1][j] - mx); sum += e[j]; }
    float inv = 1.f / sum;
#pragma unroll
    for (int j = 0; j < T_; j++) ps[h][t1][j] = e[j] * inv;
  }
  __syncthreads();
  {
    int h = d >> 4;
#pragma unroll
    for (int i = 0; i < 6; i++){
      int t = trow + i*4;
      float s = 0.f;
#pragma unroll
      for (int t2 = 0; t2 < T_; t2++) s = fmaf(ps[h][t][t2], vs[t2][d], s);
      as_[t][d] = s;
    }
  }
  __syncthreads();
  float ro[6];
  {
    float bov = bo[d];
#pragma unroll
    for (int i = 0; i < 6; i++){ int t = trow + i*4; ro[i] = bov + xs[t][d]; }
    for (int e0 = 0; e0 < 64; e0 += 16){
      float wo[16];
#pragma unroll
      for (int j = 0; j < 16; j++) wo[j] = Wo[(e0+j)*64 + d];
#pragma unroll
      for (int i = 0; i < 6; i++){
        int t = trow + i*4;
#pragma unroll
        for (int j = 0; j < 16; j++) ro[i] = fmaf(as_[t][e0+j], wo[j], ro[i]);
      }
    }
  }
  float gv = g_t[d], bv2 = b_t[d];
#pragma unroll
  for (int i = 0; i < 6; i++){
    int t = trow + i*4;
    float m = wave_sum(ro[i]) * (1.f/64.f);
    float df = ro[i] - m;
    float var = wave_sum(df*df) * (1.f/64.f);
    float y = df * rsqrtf(var + 1e-5f) * gv + bv2;
    h1[((size_t)(b*T_ + t)*N_ + n)*D_ + d] = y;
  }
}

// ---------- MFMA prop: Y = Ahat@X (per slice), fused G (+)= Y@gcWk ----------
template<typename TX>
__global__ __launch_bounds__(256, 4) void k_prop_m(
    const ushort_t* __restrict__ Ahat,  // [512][512] bf16
    const TX* __restrict__ X,           // [BT][512][64]
    const float* __restrict__ gcWk,     // [64][64] fp32
    ushort_t* __restrict__ P,
    ushort_t* __restrict__ G,
    int store_p, int accum)
{
  __shared__ __align__(16) ushort_t Ab[64][72];
  __shared__ __align__(16) ushort_t Xb[64][72];
  __shared__ __align__(16) ushort_t Yt[64][72];
  __shared__ __align__(16) ushort_t Wt[64][72];
  int tid  = threadIdx.x;
  int lane = tid & 63, w = tid >> 6;
  int mw = (w >> 1) * 32, nw = (w & 1) * 32;
  int l31 = lane & 31, lh = lane >> 5;
  int m0 = blockIdx.x * 64;
  size_t slice = (size_t)blockIdx.y * (N_ * D_);
  const TX* Xg = X + slice;

  {
    int d = tid & 63, e4 = tid >> 6;
#pragma unroll
    for (int g = 0; g < 2; g++){
      int es = (e4 + g*4) * 8;
      ushort_t tmp[8];
#pragma unroll
      for (int i = 0; i < 8; i++) tmp[i] = f2us(gcWk[(es + i)*64 + d]);
      *(uint4*)&Wt[d][es] = *(uint4*)tmp;
    }
  }

  accv16 acc = {};
  int ar = tid >> 3, ac8 = (tid & 7) * 8;
  int xn = tid & 63, xk4 = tid >> 6;
  for (int k0 = 0; k0 < N_; k0 += 64){
#pragma unroll
    for (int g = 0; g < 2; g++){
      int rr = ar + g*32;
      *(uint4*)&Ab[rr][ac8] =
        *(const uint4*)&Ahat[(size_t)(m0 + rr)*N_ + k0 + ac8];
    }
#pragma unroll
    for (int g = 0; g < 2; g++){
      int ks = (xk4 + g*4) * 8;
      ushort_t tmp[8];
#pragma unroll
      for (int i = 0; i < 8; i++) tmp[i] = f2us(ldX(Xg[(size_t)(k0 + ks + i)*D_ + xn]));
      *(uint4*)&Xb[xn][ks] = *(uint4*)tmp;
    }
    __syncthreads();
#pragma unroll
    for (int kk = 0; kk < 64; kk += 16){
      frag8 af = *(const frag8*)&Ab[mw + l31][kk + lh*8];
      frag8 bf = *(const frag8*)&Xb[nw + l31][kk + lh*8];
      acc = __builtin_amdgcn_mfma_f32_32x32x16_bf16(af, bf, acc, 0, 0, 0);
    }
    __syncthreads();
  }

#pragma unroll
  for (int r = 0; r < 16; r++){
    int row = mw + (r & 3) + 8*(r >> 2) + 4*lh;
    Yt[row][nw + l31] = f2us(acc[r]);
  }
  __syncthreads();

  if (store_p){
#pragma unroll
    for (int g = 0; g < 2; g++){
      int rr = ar + g*32;
      *(uint4*)&P[slice + (size_t)(m0 + rr)*D_ + ac8] = *(const uint4*)&Yt[rr][ac8];
    }
  }

  accv16 acc2 = {};
#pragma unroll
  for (int kk = 0; kk < 64; kk += 16){
    frag8 af = *(const frag8*)&Yt[mw + l31][kk + lh*8];
    frag8 bf = *(const frag8*)&Wt[nw + l31][kk + lh*8];
    acc2 = __builtin_amdgcn_mfma_f32_32x32x16_bf16(af, bf, acc2, 0, 0, 0);
  }
#pragma unroll
  for (int r = 0; r < 16; r++){
    int row = mw + (r & 3) + 8*(r >> 2) + 4*lh;
    Ab[row][nw + l31] = f2us(acc2[r]);
  }
  __syncthreads();
#pragma unroll
  for (int g = 0; g < 2; g++){
    int rr = ar + g*32;
    uint4 vv = *(const uint4*)&Ab[rr][ac8];
    size_t base = slice + (size_t)(m0 + rr)*D_ + ac8;
    if (accum){
      uint4 ov = *(const uint4*)&G[base];
      ushort_t* s = (ushort_t*)&vv;
      ushort_t* o = (ushort_t*)&ov;
      ushort_t res[8];
#pragma unroll
      for (int i = 0; i < 8; i++) res[i] = f2us(us2f(s[i]) + us2f(o[i]));
      *(uint4*)&G[base] = *(uint4*)res;
    } else {
      *(uint4*)&G[base] = vv;
    }
  }
}

// ---------- h2 = LN(h1 + h1@gcW0 + g12 + sum(gcb)) ; in-place on d_out ----------
__global__ __launch_bounds__(256) void k_comb(
  const ushort_t* __restrict__ g12,
  const float* __restrict__ gcW, const float* __restrict__ gcb,
  const float* __restrict__ g_g, const float* __restrict__ b_g,
  float* __restrict__ h)
{
  __shared__ float hs[32][64];
  int tid = threadIdx.x;
  size_t tok0 = (size_t)blockIdx.x * 32;
#pragma unroll
  for (int i = 0; i < 8; i++){
    int idx = tid + i*256;
    int dd = idx & 63, t = idx >> 6;
    hs[t][dd] = h[(tok0 + t)*64 + dd];
  }
  __syncthreads();
  int d = tid & 63, trow = tid >> 6;
  float acc[8];
  float bsum = gcb[d] + gcb[64+d] + gcb[128+d];
#pragma unroll
  for (int i = 0; i < 8; i++) acc[i] = bsum + us2f(g12[(tok0 + trow + i*4)*64 + d]);
  for (int e0 = 0; e0 < 64; e0 += 16){
    float w0[16];
#pragma unroll
    for (int j = 0; j < 16; j++) w0[j] = gcW[(e0+j)*64 + d];
#pragma unroll
    for (int i = 0; i < 8; i++){
      int t = trow + i*4;
#pragma unroll
      for (int j = 0; j < 16; j++) acc[i] = fmaf(hs[t][e0+j], w0[j], acc[i]);
    }
  }
  float gv = g_g[d], bv = b_g[d];
#pragma unroll
  for (int i = 0; i < 8; i++){
    int t = trow + i*4;
    float v = acc[i] + hs[t][d];
    float m = wave_sum(v) * (1.f/64.f);
    float df = v - m;
    float var = wave_sum(df*df) * (1.f/64.f);
    float y = df * rsqrtf(var + 1e-5f) * gv + bv;
    h[(tok0 + t)*64 + d] = y;
  }
}

// ---------- MFMA FFN: out = LN(h + gelu(h@W1+b1)@W2 + b2) ; in-place ----------
// 64 tokens/block, 4 waves. F processed in 2 chunks of 128.
__global__ __launch_bounds__(256, 4) void k_ffn_m(
  const ushort_t* __restrict__ W1t,   // [256 f][64 e] bf16
  const ushort_t* __restrict__ W2t,   // [64 d][256 e] bf16
  const float* __restrict__ b1, const float* __restrict__ b2,
  const float* __restrict__ g_f, const float* __restrict__ b_f,
  float* __restrict__ h)
{
  // smem: hsA 64x72 bf16 (9216) | Wc 128x72 bf16 (18432, W1c/W2c union) | Uc 64x136 bf16 (17408, Os f32 union)
  __shared__ __align__(16) char smem[9216 + 18432 + 17408];
  ushort_t (*hsA)[72]  = (ushort_t(*)[72]) smem;
  ushort_t (*W1c)[72]  = (ushort_t(*)[72]) (smem + 9216);
  ushort_t (*W2c)[136] = (ushort_t(*)[136])(smem + 9216);
  ushort_t (*Uc)[136]  = (ushort_t(*)[136])(smem + 9216 + 18432);
  float    (*Os)[65]   = (float(*)[65])    (smem + 9216 + 18432);

  int tid = threadIdx.x;
  int lane = tid & 63, w = tid >> 6;
  int l31 = lane & 31, lh = lane >> 5;
  size_t tok0 = (size_t)blockIdx.x * 64;

  // stage h tile -> bf16 A-layout
#pragma unroll
  for (int i = 0; i < 16; i++){
    int idx = tid + i*256;
    int t = idx >> 6, dd = idx & 63;
    hsA[t][dd] = f2us(h[tok0*64 + idx]);
  }

  int mw1 = (w & 1) * 32;           // phase-1 m tile
  int nA  = (w >> 1) * 32;          // phase-1 n tiles: nA, nA+64 (chunk-local)
  int mw2 = (w >> 1) * 32;          // phase-2 m tile
  int dw  = (w & 1) * 32;           // phase-2 d tile
  accv16 acc2 = {};

  for (int f0 = 0; f0 < F_; f0 += 128){
    __syncthreads();                          // Uc/Wc free
    // load W1 chunk: rows f0..f0+127 of W1t -> W1c[n][e]
    {
      int row = tid >> 1, half = (tid & 1) * 32;
      const ushort_t* src = &W1t[(size_t)(f0 + row)*64 + half];
#pragma unroll
      for (int g = 0; g < 4; g++)
        *(uint4*)&W1c[row][half + g*8] = *(const uint4*)&src[g*8];
    }
    __syncthreads();                          // hsA + W1c ready
    // phase-1 MFMA: U[64][128] = h @ W1chunk
    accv16 accA = {}, accB = {};
#pragma unroll
    for (int kk = 0; kk < 64; kk += 16){
      frag8 af = *(const frag8*)&hsA[mw1 + l31][kk + lh*8];
      frag8 b0 = *(const frag8*)&W1c[nA + l31][kk + lh*8];
      frag8 b1f = *(const frag8*)&W1c[nA + 64 + l31][kk + lh*8];
      accA = __builtin_amdgcn_mfma_f32_32x32x16_bf16(af, b0, accA, 0, 0, 0);
      accB = __builtin_amdgcn_mfma_f32_32x32x16_bf16(af, b1f, accB, 0, 0, 0);
    }
    // bias + exact GELU -> Uc (A-layout for phase 2)
    {
      float bA = b1[f0 + nA + l31];
      float bB = b1[f0 + nA + 64 + l31];
#pragma unroll
      for (int r = 0; r < 16; r++){
        int row = mw1 + (r & 3) + 8*(r >> 2) + 4*lh;
        float uA = accA[r] + bA;
        float uB = accB[r] + bB;
        Uc[row][nA + l31]      = f2us(0.5f*uA*(1.f + erff(uA*0.70710678118654752f)));
        Uc[row][nA + 64 + l31] = f2us(0.5f*uB*(1.f + erff(uB*0.70710678118654752f)));
      }
    }
    __syncthreads();                          // Uc ready; W1c reads done
    // load W2 chunk: cols f0..f0+127 of W2t -> W2c[d][e_local]
    {
      int row = tid >> 2, seg = (tid & 3) * 32;
      const ushort_t* src = &W2t[(size_t)row*256 + f0 + seg];
#pragma unroll
      for (int g = 0; g < 4; g++)
        *(uint4*)&W2c[row][seg + g*8] = *(const uint4*)&src[g*8];
    }
    __syncthreads();                          // W2c ready
    // phase-2 MFMA accumulate: O[64][64] += Uchunk @ W2chunk
#pragma unroll
    for (int kk = 0; kk < 128; kk += 16){
      frag8 af = *(const frag8*)&Uc[mw2 + l31][kk + lh*8];
      frag8 bf = *(const frag8*)&W2c[dw + l31][kk + lh*8];
      acc2 = __builtin_amdgcn_mfma_f32_32x32x16_bf16(af, bf, acc2, 0, 0, 0);
    }
  }
  __syncthreads();                            // Uc region free -> Os
  {
    float b2v = b2[dw + l31];
#pragma unroll
    for (int r = 0; r < 16; r++){
      int row = mw2 + (r & 3) + 8*(r >> 2) + 4*lh;
      Os[row][dw + l31] = acc2[r] + b2v;
    }
  }
  __syncthreads();
  // residual (re-read h) + LN + store
  {
    int d = tid & 63, trow = tid >> 6;
    float gv = g_f[d], bv = b_f[d];
#pragma unroll
    for (int i = 0; i < 16; i++){
      int t = trow + i*4;
      float v = Os[t][d] + h[(tok0 + t)*64 + d];
      float m = wave_sum(v) * (1.f/64.f);
      float df = v - m;
      float var = wave_sum(df*df) * (1.f/64.f);
      float y = df * rsqrtf(var + 1e-5f) * gv + bv;
      h[(tok0 + t)*64 + d] = y;
    }
  }
}

extern "C" void kernel_launch(void* const* d_in, const int* in_sizes, int n_in,
                              void* d_out, int out_size, void* d_ws, size_t ws_size,
                              hipStream_t stream)
{
  const float* x   = (const float*)d_in[0];
  const float* adj = (const float*)d_in[1];
  const float* Wq  = (const float*)d_in[2];
  const float* bq  = (const float*)d_in[3];
  const float* Wk  = (const float*)d_in[4];
  const float* bk  = (const float*)d_in[5];
  const float* Wv  = (const float*)d_in[6];
  const float* bv  = (const float*)d_in[7];
  const float* Wo  = (const float*)d_in[8];
  const float* bo  = (const float*)d_in[9];
  const float* gcW = (const float*)d_in[10];
  const float* gcb = (const float*)d_in[11];
  const float* W1  = (const float*)d_in[12];
  const float* b1  = (const float*)d_in[13];
  const float* W2  = (const float*)d_in[14];
  const float* b2  = (const float*)d_in[15];
  const float* g_t = (const float*)d_in[16];
  const float* b_t = (const float*)d_in[17];
  const float* g_g = (const float*)d_in[18];
  const float* b_g = (const float*)d_in[19];
  const float* g_f = (const float*)d_in[20];
  const float* b_f = (const float*)d_in[21];

  // ws (~51 MB): dinv 2KB | Ahat bf16 512KB | p 25.2MB | g12 25.2MB | W1t 32KB | W2t 32KB
  const size_t MD = (size_t)B_*T_*N_*D_;
  float* dinv = (float*)d_ws;
  ushort_t* AhatB = (ushort_t*)(dinv + 512);
  ushort_t* p   = AhatB + (size_t)N_*N_;
  ushort_t* g12 = p + MD;
  ushort_t* W1t = g12 + MD;
  ushort_t* W2t = W1t + 256*64;
  float* h = (float*)d_out;

  k_dinv<<<N_, 64, 0, stream>>>(adj, dinv);
  k_ahat<<<(N_*N_)/256, 256, 0, stream>>>(adj, dinv, AhatB);
  k_wprep<<<64, 256, 0, stream>>>(W1, W2, W1t, W2t);
  k_attn<<<B_*N_, 256, 0, stream>>>(x, Wq,bq, Wk,bk, Wv,bv, Wo,bo, g_t,b_t, h);
  k_prop_m<float><<<dim3(N_/64, B_*T_), 256, 0, stream>>>(AhatB, h, gcW + 4096, p, g12, 1, 0);
  k_prop_m<ushort_t><<<dim3(N_/64, B_*T_), 256, 0, stream>>>(AhatB, p, gcW + 8192, p, g12, 0, 1);
  k_comb<<<(int)(MD/D_/32), 256, 0, stream>>>(g12, gcW, gcb, g_g, b_g, h);
  k_ffn_m<<<(int)(MD/D_/64), 256, 0, stream>>>(W1t, W2t, b1, b2, g_f, b_f, h);
}

// Round 6
// 557.207 us; speedup vs baseline: 3.0317x; 1.1222x over previous
//
#include <hip/hip_runtime.h>
#include <hip/hip_bf16.h>
#include <math.h>

typedef __hip_bfloat16 bf16;
typedef unsigned short ushort_t;

__device__ __forceinline__ float us2f(ushort_t u){
  union { unsigned u; float f; } v; v.u = ((unsigned)u) << 16; return v.f;
}
__device__ __forceinline__ ushort_t f2us(float f){
  union { float f; unsigned u; } v; v.f = f;
  unsigned r = v.u + 0x7fff + ((v.u >> 16) & 1);   // RNE
  return (ushort_t)(r >> 16);
}
__device__ __forceinline__ float ldX(float v){ return v; }
__device__ __forceinline__ float ldX(ushort_t v){ return us2f(v); }

#define B_ 16
#define T_ 24
#define N_ 512
#define D_ 64
#define F_ 256

typedef __attribute__((ext_vector_type(8)))  short  frag8;
typedef __attribute__((ext_vector_type(16))) float  accv16;

__device__ __forceinline__ float wave_sum(float v){
#pragma unroll
  for (int off = 32; off > 0; off >>= 1) v += __shfl_xor(v, off, 64);
  return v;
}

// ---------- degree^-1/2 ----------
__global__ __launch_bounds__(64) void k_dinv(const float* __restrict__ adj,
                                             float* __restrict__ dinv){
  int m = blockIdx.x;
  float s = 0.f;
  for (int n = threadIdx.x; n < N_; n += 64) s += adj[m*N_ + n];
  s = wave_sum(s);
  if (threadIdx.x == 0){
    float deg = s + 1.0f;
    dinv[m] = rsqrtf(fmaxf(deg, 1e-12f));
  }
}

// ---------- Ahat (bf16) = dinv_m * (adj + I) * dinv_n ----------
__global__ __launch_bounds__(256) void k_ahat(const float* __restrict__ adj,
                                              const float* __restrict__ dinv,
                                              ushort_t* __restrict__ AhatB){
  int idx = blockIdx.x*256 + threadIdx.x;
  int m = idx >> 9, n = idx & (N_-1);
  float a = adj[idx] + (m == n ? 1.f : 0.f);
  AhatB[idx] = f2us(dinv[m]*a*dinv[n]);
}

// ---------- pre-transpose weights to bf16 B-operand layout [dout][e] ----------
__global__ __launch_bounds__(256) void k_wprep(
    const float* __restrict__ W1, const float* __restrict__ W2,
    const float* __restrict__ Wq, const float* __restrict__ Wk,
    const float* __restrict__ Wv, const float* __restrict__ Wo,
    ushort_t* __restrict__ W1t, ushort_t* __restrict__ W2t,
    ushort_t* __restrict__ Wqt, ushort_t* __restrict__ Wkt,
    ushort_t* __restrict__ Wvt, ushort_t* __restrict__ Wot){
  int o = blockIdx.x*256 + threadIdx.x;   // 0..16383
  int f = o >> 6, e = o & 63;
  W1t[o] = f2us(W1[e*256 + f]);
  int d = o >> 8, e2 = o & 255;
  W2t[o] = f2us(W2[e2*64 + d]);
  if (o < 4096){
    int dd = o >> 6, ee = o & 63;
    Wqt[o] = f2us(Wq[ee*64 + dd]);
    Wkt[o] = f2us(Wk[ee*64 + dd]);
    Wvt[o] = f2us(Wv[ee*64 + dd]);
    Wot[o] = f2us(Wo[ee*64 + dd]);
  }
}

// ---------- MFMA attention: 2 nodes (48 tokens) per block ----------
__global__ __launch_bounds__(256) void k_attn_m(
    const float* __restrict__ x,
    const ushort_t* __restrict__ Wqt, const float* __restrict__ bq,
    const ushort_t* __restrict__ Wkt, const float* __restrict__ bk,
    const ushort_t* __restrict__ Wvt, const float* __restrict__ bv,
    const ushort_t* __restrict__ Wot, const float* __restrict__ bo,
    const float* __restrict__ g_t, const float* __restrict__ b_t,
    float* __restrict__ h1)
{
  // smem map (63.75 KB): xsA/aA 9216 | Wb 9216 | qs 9216 | ks 9216 | vs 9216 | ps 19200
  // Os (fp32 64x65 = 16640) aliases qs+ks after scores are consumed.
  __shared__ __align__(16) char smem[65280];
  ushort_t (*xsA)[72] = (ushort_t(*)[72]) smem;
  ushort_t (*Wb)[72]  = (ushort_t(*)[72])(smem +  9216);
  ushort_t (*qs)[72]  = (ushort_t(*)[72])(smem + 18432);
  ushort_t (*ks)[72]  = (ushort_t(*)[72])(smem + 27648);
  ushort_t (*vs)[72]  = (ushort_t(*)[72])(smem + 36864);
  float    (*ps)[24][25] = (float(*)[24][25])(smem + 46080);  // [8 = node*4+h]
  float    (*Os)[65]  = (float(*)[65])   (smem + 18432);

  int tid = threadIdx.x;
  int lane = tid & 63, w = tid >> 6;
  int l31 = lane & 31, lh = lane >> 5;
  int mt = (w >> 1) * 32, nt = (w & 1) * 32;
  int b = blockIdx.x >> 8;
  int n0 = (blockIdx.x & 255) * 2;

  // stage x (rows 0..47 = node*24+t; rows 48..63 zero) in bf16 A-layout
#pragma unroll
  for (int i = 0; i < 16; i++){
    int idx = tid + i*256;
    int row = idx >> 6, d = idx & 63;
    ushort_t vv = 0;
    if (row < 48){
      int node = row / 24, t = row - node*24;
      vv = f2us(x[(((size_t)b*T_ + t)*N_ + n0 + node)*D_ + d]);
    }
    xsA[row][d] = vv;
  }
  int wr = tid >> 3, wc = (tid & 7) * 8;
  *(uint4*)&Wb[wr][wc]    = *(const uint4*)&Wqt[(size_t)wr*64 + wc];
  *(uint4*)&Wb[wr+32][wc] = *(const uint4*)&Wqt[(size_t)(wr+32)*64 + wc];
  __syncthreads();

  // ---- QKV projections via MFMA ----
  for (int pj = 0; pj < 3; pj++){
    accv16 a = {};
#pragma unroll
    for (int kk = 0; kk < 64; kk += 16){
      frag8 af = *(const frag8*)&xsA[mt + l31][kk + lh*8];
      frag8 bf = *(const frag8*)&Wb[nt + l31][kk + lh*8];
      a = __builtin_amdgcn_mfma_f32_32x32x16_bf16(af, bf, a, 0, 0, 0);
    }
    float bias = (pj==0 ? bq : pj==1 ? bk : bv)[nt + l31];
    ushort_t (*dst)[72] = (pj==0 ? qs : pj==1 ? ks : vs);
#pragma unroll
    for (int r = 0; r < 16; r++){
      int row = mt + (r & 3) + 8*(r >> 2) + 4*lh;
      dst[row][nt + l31] = f2us(a[r] + bias);
    }
    __syncthreads();     // Wb reads done; dst visible downstream
    if (pj < 2){
      const ushort_t* Wn = (pj==0 ? Wkt : Wvt);
      *(uint4*)&Wb[wr][wc]    = *(const uint4*)&Wn[(size_t)wr*64 + wc];
      *(uint4*)&Wb[wr+32][wc] = *(const uint4*)&Wn[(size_t)(wr+32)*64 + wc];
      __syncthreads();
    } else {
      // preload Wo; visibility guaranteed by the syncs before the Wo MFMA
      *(uint4*)&Wb[wr][wc]    = *(const uint4*)&Wot[(size_t)wr*64 + wc];
      *(uint4*)&Wb[wr+32][wc] = *(const uint4*)&Wot[(size_t)(wr+32)*64 + wc];
    }
  }

  // ---- scores (vector): 2 nodes x 4 heads x 24 x 24 ----
  for (int i = tid; i < 4608; i += 256){
    int node = i / 2304, r = i - node*2304;
    int h = r / 576, rr = r - h*576;
    int t1 = rr / 24, t2 = rr - t1*24;
    int qrow = node*24 + t1, krow = node*24 + t2;
    int hb = h*16;
    float s = 0.f;
#pragma unroll
    for (int dd = 0; dd < 16; dd++)
      s += us2f(qs[qrow][hb+dd]) * us2f(ks[krow][hb+dd]);
    ps[node*4 + h][t1][t2] = s * 0.25f;
  }
  __syncthreads();
  // ---- softmax over t2 (192 rows) ----
  if (tid < 192){
    int g = tid / 24, t1 = tid - (tid/24)*24;
    float mx = -1e30f;
#pragma unroll
    for (int j = 0; j < 24; j++) mx = fmaxf(mx, ps[g][t1][j]);
    float e[24]; float sum = 0.f;
#pragma unroll
    for (int j = 0; j < 24; j++){ e[j] = __expf(ps[g][t1][j] - mx); sum += e[j]; }
    float inv = 1.f / sum;
#pragma unroll
    for (int j = 0; j < 24; j++) ps[g][t1][j] = e[j] * inv;
  }
  __syncthreads();
  // ---- PV -> aA (bf16 A-layout, aliases xsA; zero-pad rows 48..63) ----
#pragma unroll
  for (int i = 0; i < 16; i++){
    int idx = tid + i*256;
    int row = idx >> 6, d = idx & 63;
    ushort_t outv = 0;
    if (row < 48){
      int node = row / 24, t = row - node*24;
      int g = node*4 + (d >> 4);
      float s = 0.f;
#pragma unroll
      for (int t2 = 0; t2 < 24; t2++)
        s += ps[g][t][t2] * us2f(vs[node*24 + t2][d]);
      outv = f2us(s);
    }
    xsA[row][d] = outv;
  }
  __syncthreads();
  // ---- Wo MFMA ----
  accv16 ao = {};
#pragma unroll
  for (int kk = 0; kk < 64; kk += 16){
    frag8 af = *(const frag8*)&xsA[mt + l31][kk + lh*8];
    frag8 bf = *(const frag8*)&Wb[nt + l31][kk + lh*8];
    ao = __builtin_amdgcn_mfma_f32_32x32x16_bf16(af, bf, ao, 0, 0, 0);
  }
  {
    float bov = bo[nt + l31];
#pragma unroll
    for (int r = 0; r < 16; r++){
      int row = mt + (r & 3) + 8*(r >> 2) + 4*lh;
      Os[row][nt + l31] = ao[r] + bov;
    }
  }
  __syncthreads();
  // ---- residual (exact fp32 x re-read) + LN + store ----
  {
    float gv = g_t[lane], bvv = b_t[lane];
#pragma unroll
    for (int i = 0; i < 12; i++){
      int row = w + i*4;
      int node = row / 24, t = row - node*24;
      size_t gaddr = (((size_t)b*T_ + t)*N_ + n0 + node)*D_ + lane;
      float v = Os[row][lane] + x[gaddr];
      float m = wave_sum(v) * (1.f/64.f);
      float df = v - m;
      float var = wave_sum(df*df) * (1.f/64.f);
      h1[gaddr] = df * rsqrtf(var + 1e-5f) * gv + bvv;
    }
  }
}

// ---------- MFMA prop: Y = Ahat@X (per slice), fused G (+)= Y@gcWk ----------
template<typename TX>
__global__ __launch_bounds__(256, 4) void k_prop_m(
    const ushort_t* __restrict__ Ahat,  // [512][512] bf16
    const TX* __restrict__ X,           // [BT][512][64]
    const float* __restrict__ gcWk,     // [64][64] fp32
    ushort_t* __restrict__ P,
    ushort_t* __restrict__ G,
    int store_p, int accum)
{
  __shared__ __align__(16) ushort_t Ab[64][72];
  __shared__ __align__(16) ushort_t Xb[64][72];
  __shared__ __align__(16) ushort_t Yt[64][72];
  __shared__ __align__(16) ushort_t Wt[64][72];
  int tid  = threadIdx.x;
  int lane = tid & 63, w = tid >> 6;
  int mw = (w >> 1) * 32, nw = (w & 1) * 32;
  int l31 = lane & 31, lh = lane >> 5;
  int m0 = blockIdx.x * 64;
  size_t slice = (size_t)blockIdx.y * (N_ * D_);
  const TX* Xg = X + slice;

  {
    int d = tid & 63, e4 = tid >> 6;
#pragma unroll
    for (int g = 0; g < 2; g++){
      int es = (e4 + g*4) * 8;
      ushort_t tmp[8];
#pragma unroll
      for (int i = 0; i < 8; i++) tmp[i] = f2us(gcWk[(es + i)*64 + d]);
      *(uint4*)&Wt[d][es] = *(uint4*)tmp;
    }
  }

  accv16 acc = {};
  int ar = tid >> 3, ac8 = (tid & 7) * 8;
  int xn = tid & 63, xk4 = tid >> 6;
  for (int k0 = 0; k0 < N_; k0 += 64){
#pragma unroll
    for (int g = 0; g < 2; g++){
      int rr = ar + g*32;
      *(uint4*)&Ab[rr][ac8] =
        *(const uint4*)&Ahat[(size_t)(m0 + rr)*N_ + k0 + ac8];
    }
#pragma unroll
    for (int g = 0; g < 2; g++){
      int ks = (xk4 + g*4) * 8;
      ushort_t tmp[8];
#pragma unroll
      for (int i = 0; i < 8; i++) tmp[i] = f2us(ldX(Xg[(size_t)(k0 + ks + i)*D_ + xn]));
      *(uint4*)&Xb[xn][ks] = *(uint4*)tmp;
    }
    __syncthreads();
#pragma unroll
    for (int kk = 0; kk < 64; kk += 16){
      frag8 af = *(const frag8*)&Ab[mw + l31][kk + lh*8];
      frag8 bf = *(const frag8*)&Xb[nw + l31][kk + lh*8];
      acc = __builtin_amdgcn_mfma_f32_32x32x16_bf16(af, bf, acc, 0, 0, 0);
    }
    __syncthreads();
  }

#pragma unroll
  for (int r = 0; r < 16; r++){
    int row = mw + (r & 3) + 8*(r >> 2) + 4*lh;
    Yt[row][nw + l31] = f2us(acc[r]);
  }
  __syncthreads();

  if (store_p){
#pragma unroll
    for (int g = 0; g < 2; g++){
      int rr = ar + g*32;
      *(uint4*)&P[slice + (size_t)(m0 + rr)*D_ + ac8] = *(const uint4*)&Yt[rr][ac8];
    }
  }

  accv16 acc2 = {};
#pragma unroll
  for (int kk = 0; kk < 64; kk += 16){
    frag8 af = *(const frag8*)&Yt[mw + l31][kk + lh*8];
    frag8 bf = *(const frag8*)&Wt[nw + l31][kk + lh*8];
    acc2 = __builtin_amdgcn_mfma_f32_32x32x16_bf16(af, bf, acc2, 0, 0, 0);
  }
#pragma unroll
  for (int r = 0; r < 16; r++){
    int row = mw + (r & 3) + 8*(r >> 2) + 4*lh;
    Ab[row][nw + l31] = f2us(acc2[r]);
  }
  __syncthreads();
#pragma unroll
  for (int g = 0; g < 2; g++){
    int rr = ar + g*32;
    uint4 vv = *(const uint4*)&Ab[rr][ac8];
    size_t base = slice + (size_t)(m0 + rr)*D_ + ac8;
    if (accum){
      uint4 ov = *(const uint4*)&G[base];
      ushort_t* s = (ushort_t*)&vv;
      ushort_t* o = (ushort_t*)&ov;
      ushort_t res[8];
#pragma unroll
      for (int i = 0; i < 8; i++) res[i] = f2us(us2f(s[i]) + us2f(o[i]));
      *(uint4*)&G[base] = *(uint4*)res;
    } else {
      *(uint4*)&G[base] = vv;
    }
  }
}

// ---------- h2 = LN(h1 + h1@gcW0 + g12 + sum(gcb)) ; in-place on d_out ----------
__global__ __launch_bounds__(256) void k_comb(
  const ushort_t* __restrict__ g12,
  const float* __restrict__ gcW, const float* __restrict__ gcb,
  const float* __restrict__ g_g, const float* __restrict__ b_g,
  float* __restrict__ h)
{
  __shared__ float hs[32][64];
  int tid = threadIdx.x;
  size_t tok0 = (size_t)blockIdx.x * 32;
#pragma unroll
  for (int i = 0; i < 8; i++){
    int idx = tid + i*256;
    int dd = idx & 63, t = idx >> 6;
    hs[t][dd] = h[(tok0 + t)*64 + dd];
  }
  __syncthreads();
  int d = tid & 63, trow = tid >> 6;
  float acc[8];
  float bsum = gcb[d] + gcb[64+d] + gcb[128+d];
#pragma unroll
  for (int i = 0; i < 8; i++) acc[i] = bsum + us2f(g12[(tok0 + trow + i*4)*64 + d]);
  for (int e0 = 0; e0 < 64; e0 += 16){
    float w0[16];
#pragma unroll
    for (int j = 0; j < 16; j++) w0[j] = gcW[(e0+j)*64 + d];
#pragma unroll
    for (int i = 0; i < 8; i++){
      int t = trow + i*4;
#pragma unroll
      for (int j = 0; j < 16; j++) acc[i] = fmaf(hs[t][e0+j], w0[j], acc[i]);
    }
  }
  float gv = g_g[d], bv = b_g[d];
#pragma unroll
  for (int i = 0; i < 8; i++){
    int t = trow + i*4;
    float v = acc[i] + hs[t][d];
    float m = wave_sum(v) * (1.f/64.f);
    float df = v - m;
    float var = wave_sum(df*df) * (1.f/64.f);
    float y = df * rsqrtf(var + 1e-5f) * gv + bv;
    h[(tok0 + t)*64 + d] = y;
  }
}

// ---------- MFMA FFN: out = LN(h + gelu(h@W1+b1)@W2 + b2) ; in-place ----------
__global__ __launch_bounds__(256, 4) void k_ffn_m(
  const ushort_t* __restrict__ W1t,   // [256 f][64 e] bf16
  const ushort_t* __restrict__ W2t,   // [64 d][256 e] bf16
  const float* __restrict__ b1, const float* __restrict__ b2,
  const float* __restrict__ g_f, const float* __restrict__ b_f,
  float* __restrict__ h)
{
  __shared__ __align__(16) char smem[9216 + 18432 + 17408];
  ushort_t (*hsA)[72]  = (ushort_t(*)[72]) smem;
  ushort_t (*W1c)[72]  = (ushort_t(*)[72]) (smem + 9216);
  ushort_t (*W2c)[136] = (ushort_t(*)[136])(smem + 9216);
  ushort_t (*Uc)[136]  = (ushort_t(*)[136])(smem + 9216 + 18432);
  float    (*Os)[65]   = (float(*)[65])    (smem + 9216 + 18432);

  int tid = threadIdx.x;
  int lane = tid & 63, w = tid >> 6;
  int l31 = lane & 31, lh = lane >> 5;
  size_t tok0 = (size_t)blockIdx.x * 64;

#pragma unroll
  for (int i = 0; i < 16; i++){
    int idx = tid + i*256;
    int t = idx >> 6, dd = idx & 63;
    hsA[t][dd] = f2us(h[tok0*64 + idx]);
  }

  int mw1 = (w & 1) * 32;
  int nA  = (w >> 1) * 32;
  int mw2 = (w >> 1) * 32;
  int dw  = (w & 1) * 32;
  accv16 acc2 = {};

  for (int f0 = 0; f0 < F_; f0 += 128){
    __syncthreads();
    {
      int row = tid >> 1, half = (tid & 1) * 32;
      const ushort_t* src = &W1t[(size_t)(f0 + row)*64 + half];
#pragma unroll
      for (int g = 0; g < 4; g++)
        *(uint4*)&W1c[row][half + g*8] = *(const uint4*)&src[g*8];
    }
    __syncthreads();
    accv16 accA = {}, accB = {};
#pragma unroll
    for (int kk = 0; kk < 64; kk += 16){
      frag8 af = *(const frag8*)&hsA[mw1 + l31][kk + lh*8];
      frag8 b0 = *(const frag8*)&W1c[nA + l31][kk + lh*8];
      frag8 b1f = *(const frag8*)&W1c[nA + 64 + l31][kk + lh*8];
      accA = __builtin_amdgcn_mfma_f32_32x32x16_bf16(af, b0, accA, 0, 0, 0);
      accB = __builtin_amdgcn_mfma_f32_32x32x16_bf16(af, b1f, accB, 0, 0, 0);
    }
    {
      float bA = b1[f0 + nA + l31];
      float bB = b1[f0 + nA + 64 + l31];
#pragma unroll
      for (int r = 0; r < 16; r++){
        int row = mw1 + (r & 3) + 8*(r >> 2) + 4*lh;
        float uA = accA[r] + bA;
        float uB = accB[r] + bB;
        Uc[row][nA + l31]      = f2us(0.5f*uA*(1.f + erff(uA*0.70710678118654752f)));
        Uc[row][nA + 64 + l31] = f2us(0.5f*uB*(1.f + erff(uB*0.70710678118654752f)));
      }
    }
    __syncthreads();
    {
      int row = tid >> 2, seg = (tid & 3) * 32;
      const ushort_t* src = &W2t[(size_t)row*256 + f0 + seg];
#pragma unroll
      for (int g = 0; g < 4; g++)
        *(uint4*)&W2c[row][seg + g*8] = *(const uint4*)&src[g*8];
    }
    __syncthreads();
#pragma unroll
    for (int kk = 0; kk < 128; kk += 16){
      frag8 af = *(const frag8*)&Uc[mw2 + l31][kk + lh*8];
      frag8 bf = *(const frag8*)&W2c[dw + l31][kk + lh*8];
      acc2 = __builtin_amdgcn_mfma_f32_32x32x16_bf16(af, bf, acc2, 0, 0, 0);
    }
  }
  __syncthreads();
  {
    float b2v = b2[dw + l31];
#pragma unroll
    for (int r = 0; r < 16; r++){
      int row = mw2 + (r & 3) + 8*(r >> 2) + 4*lh;
      Os[row][dw + l31] = acc2[r] + b2v;
    }
  }
  __syncthreads();
  {
    int d = tid & 63, trow = tid >> 6;
    float gv = g_f[d], bv = b_f[d];
#pragma unroll
    for (int i = 0; i < 16; i++){
      int t = trow + i*4;
      float v = Os[t][d] + h[(tok0 + t)*64 + d];
      float m = wave_sum(v) * (1.f/64.f);
      float df = v - m;
      float var = wave_sum(df*df) * (1.f/64.f);
      float y = df * rsqrtf(var + 1e-5f) * gv + bv;
      h[(tok0 + t)*64 + d] = y;
    }
  }
}

extern "C" void kernel_launch(void* const* d_in, const int* in_sizes, int n_in,
                              void* d_out, int out_size, void* d_ws, size_t ws_size,
                              hipStream_t stream)
{
  const float* x   = (const float*)d_in[0];
  const float* adj = (const float*)d_in[1];
  const float* Wq  = (const float*)d_in[2];
  const float* bq  = (const float*)d_in[3];
  const float* Wk  = (const float*)d_in[4];
  const float* bk  = (const float*)d_in[5];
  const float* Wv  = (const float*)d_in[6];
  const float* bv  = (const float*)d_in[7];
  const float* Wo  = (const float*)d_in[8];
  const float* bo  = (const float*)d_in[9];
  const float* gcW = (const float*)d_in[10];
  const float* gcb = (const float*)d_in[11];
  const float* W1  = (const float*)d_in[12];
  const float* b1  = (const float*)d_in[13];
  const float* W2  = (const float*)d_in[14];
  const float* b2  = (const float*)d_in[15];
  const float* g_t = (const float*)d_in[16];
  const float* b_t = (const float*)d_in[17];
  const float* g_g = (const float*)d_in[18];
  const float* b_g = (const float*)d_in[19];
  const float* g_f = (const float*)d_in[20];
  const float* b_f = (const float*)d_in[21];

  // ws (~51 MB): dinv 2KB | Ahat bf16 512KB | p 25.2MB | g12 25.2MB | W1t/W2t 64KB | Wqt..Wot 32KB
  const size_t MD = (size_t)B_*T_*N_*D_;
  float* dinv = (float*)d_ws;
  ushort_t* AhatB = (ushort_t*)(dinv + 512);
  ushort_t* p   = AhatB + (size_t)N_*N_;
  ushort_t* g12 = p + MD;
  ushort_t* W1t = g12 + MD;
  ushort_t* W2t = W1t + 256*64;
  ushort_t* Wqt = W2t + 64*256;
  ushort_t* Wkt = Wqt + 4096;
  ushort_t* Wvt = Wkt + 4096;
  ushort_t* Wot = Wvt + 4096;
  float* h = (float*)d_out;

  k_dinv<<<N_, 64, 0, stream>>>(adj, dinv);
  k_ahat<<<(N_*N_)/256, 256, 0, stream>>>(adj, dinv, AhatB);
  k_wprep<<<64, 256, 0, stream>>>(W1, W2, Wq, Wk, Wv, Wo, W1t, W2t, Wqt, Wkt, Wvt, Wot);
  k_attn_m<<<B_*N_/2, 256, 0, stream>>>(x, Wqt,bq, Wkt,bk, Wvt,bv, Wot,bo, g_t,b_t, h);
  k_prop_m<float><<<dim3(N_/64, B_*T_), 256, 0, stream>>>(AhatB, h, gcW + 4096, p, g12, 1, 0);
  k_prop_m<ushort_t><<<dim3(N_/64, B_*T_), 256, 0, stream>>>(AhatB, p, gcW + 8192, p, g12, 0, 1);
  k_comb<<<(int)(MD/D_/32), 256, 0, stream>>>(g12, gcW, gcb, g_g, b_g, h);
  k_ffn_m<<<(int)(MD/D_/64), 256, 0, stream>>>(W1t, W2t, b1, b2, g_f, b_f, h);
}

// Round 7
// 480.402 us; speedup vs baseline: 3.5163x; 1.1599x over previous
//
#include <hip/hip_runtime.h>
#include <hip/hip_bf16.h>
#include <math.h>

typedef __hip_bfloat16 bf16;
typedef unsigned short ushort_t;

__device__ __forceinline__ float us2f(ushort_t u){
  union { unsigned u; float f; } v; v.u = ((unsigned)u) << 16; return v.f;
}
__device__ __forceinline__ ushort_t f2us(float f){
  union { float f; unsigned u; } v; v.f = f;
  unsigned r = v.u + 0x7fff + ((v.u >> 16) & 1);   // RNE
  return (ushort_t)(r >> 16);
}
__device__ __forceinline__ float ldX(float v){ return v; }
__device__ __forceinline__ float ldX(ushort_t v){ return us2f(v); }

#define B_ 16
#define T_ 24
#define N_ 512
#define D_ 64
#define F_ 256

typedef __attribute__((ext_vector_type(8)))  short  frag8;
typedef __attribute__((ext_vector_type(16))) float  accv16;

__device__ __forceinline__ float wave_sum(float v){
#pragma unroll
  for (int off = 32; off > 0; off >>= 1) v += __shfl_xor(v, off, 64);
  return v;
}

// ---------- degree^-1/2 ----------
__global__ __launch_bounds__(64) void k_dinv(const float* __restrict__ adj,
                                             float* __restrict__ dinv){
  int m = blockIdx.x;
  float s = 0.f;
  for (int n = threadIdx.x; n < N_; n += 64) s += adj[m*N_ + n];
  s = wave_sum(s);
  if (threadIdx.x == 0){
    float deg = s + 1.0f;
    dinv[m] = rsqrtf(fmaxf(deg, 1e-12f));
  }
}

// ---------- Ahat (bf16) = dinv_m * (adj + I) * dinv_n ----------
__global__ __launch_bounds__(256) void k_ahat(const float* __restrict__ adj,
                                              const float* __restrict__ dinv,
                                              ushort_t* __restrict__ AhatB){
  int idx = blockIdx.x*256 + threadIdx.x;
  int m = idx >> 9, n = idx & (N_-1);
  float a = adj[idx] + (m == n ? 1.f : 0.f);
  AhatB[idx] = f2us(dinv[m]*a*dinv[n]);
}

// ---------- pre-transpose weights to bf16 B-operand layout [dout][e] ----------
__global__ __launch_bounds__(256) void k_wprep(
    const float* __restrict__ W1, const float* __restrict__ W2,
    const float* __restrict__ Wq, const float* __restrict__ Wk,
    const float* __restrict__ Wv, const float* __restrict__ Wo,
    ushort_t* __restrict__ W1t, ushort_t* __restrict__ W2t,
    ushort_t* __restrict__ Wqt, ushort_t* __restrict__ Wkt,
    ushort_t* __restrict__ Wvt, ushort_t* __restrict__ Wot){
  int o = blockIdx.x*256 + threadIdx.x;   // 0..16383
  int f = o >> 6, e = o & 63;
  W1t[o] = f2us(W1[e*256 + f]);
  int d = o >> 8, e2 = o & 255;
  W2t[o] = f2us(W2[e2*64 + d]);
  if (o < 4096){
    int dd = o >> 6, ee = o & 63;
    Wqt[o] = f2us(Wq[ee*64 + dd]);
    Wkt[o] = f2us(Wk[ee*64 + dd]);
    Wvt[o] = f2us(Wv[ee*64 + dd]);
    Wot[o] = f2us(Wo[ee*64 + dd]);
  }
}

// ---------- full-MFMA attention: 2 nodes (48 tokens) per block ----------
// LDS 53248 B: xsA 9216 | Wb 9216 | [qs+ks 18432 -> psb 16384 -> Os 16640] | vsT 16384
__global__ __launch_bounds__(256, 3) void k_attn_m(
    const float* __restrict__ x,
    const ushort_t* __restrict__ Wqt, const float* __restrict__ bq,
    const ushort_t* __restrict__ Wkt, const float* __restrict__ bk,
    const ushort_t* __restrict__ Wvt, const float* __restrict__ bv,
    const ushort_t* __restrict__ Wot, const float* __restrict__ bo,
    const float* __restrict__ g_t, const float* __restrict__ b_t,
    float* __restrict__ h1)
{
  __shared__ __align__(16) char smem[53248];
  ushort_t (*xsA)[72] = (ushort_t(*)[72]) smem;                 // 64x72 bf16
  ushort_t (*Wb)[72]  = (ushort_t(*)[72])(smem +  9216);        // 64x72 bf16
  ushort_t (*qs)[72]  = (ushort_t(*)[72])(smem + 18432);        // 64x72 bf16
  ushort_t (*ks)[72]  = (ushort_t(*)[72])(smem + 27648);        // 64x72 bf16
  ushort_t (*psb)[32] = (ushort_t(*)[32])(smem + 18432);        // [8*32][32] bf16 (alias qs/ks)
  float    (*Os)[65]  = (float(*)[65])   (smem + 18432);        // 64x65 f32 (alias)
  ushort_t (*vsT)[32] = (ushort_t(*)[32])(smem + 36864);        // [8*32][32] bf16

  int tid = threadIdx.x;
  int lane = tid & 63, w = tid >> 6;
  int l31 = lane & 31, lh = lane >> 5;
  int mt = (w >> 1) * 32, nt = (w & 1) * 32;
  int b = blockIdx.x >> 8;
  int n0 = (blockIdx.x & 255) * 2;

  // zero vsT (covers d-rows 16..31 and t2-tail 24..31)
  {
    uint4 z4 = {0,0,0,0};
#pragma unroll
    for (int i = 0; i < 4; i++)
      *(uint4*)(smem + 36864 + (tid + i*256)*16) = z4;
  }
  // stage x (rows 0..47 = node*24+t; rows 48..63 zero) in bf16 A-layout
#pragma unroll
  for (int i = 0; i < 16; i++){
    int idx = tid + i*256;
    int row = idx >> 6, d = idx & 63;
    ushort_t vv = 0;
    if (row < 48){
      int node = row / 24, t = row - node*24;
      vv = f2us(x[(((size_t)b*T_ + t)*N_ + n0 + node)*D_ + d]);
    }
    xsA[row][d] = vv;
  }
  int wr = tid >> 3, wc = (tid & 7) * 8;
  *(uint4*)&Wb[wr][wc]    = *(const uint4*)&Wqt[(size_t)wr*64 + wc];
  *(uint4*)&Wb[wr+32][wc] = *(const uint4*)&Wqt[(size_t)(wr+32)*64 + wc];
  __syncthreads();

  // ---- QKV projections via MFMA (V written transposed into vsT) ----
  for (int pj = 0; pj < 3; pj++){
    accv16 a = {};
#pragma unroll
    for (int kk = 0; kk < 64; kk += 16){
      frag8 af = *(const frag8*)&xsA[mt + l31][kk + lh*8];
      frag8 bf = *(const frag8*)&Wb[nt + l31][kk + lh*8];
      a = __builtin_amdgcn_mfma_f32_32x32x16_bf16(af, bf, a, 0, 0, 0);
    }
    float bias = (pj==0 ? bq : pj==1 ? bk : bv)[nt + l31];
    if (pj < 2){
      ushort_t (*dst)[72] = (pj==0 ? qs : ks);
#pragma unroll
      for (int r = 0; r < 16; r++){
        int row = mt + (r & 3) + 8*(r >> 2) + 4*lh;
        dst[row][nt + l31] = f2us(a[r] + bias);
      }
    } else {
      int cl = nt + l31;
      int vrow = ((cl >> 4) << 5) + (cl & 15);    // head*32 + d_local (node added below)
#pragma unroll
      for (int r = 0; r < 16; r++){
        int row = mt + (r & 3) + 8*(r >> 2) + 4*lh;
        if (row < 48){
          int node = (row >= 24);
          int t2 = row - node*24;
          vsT[node*128 + vrow][t2] = f2us(a[r] + bias);
        }
      }
    }
    __syncthreads();     // Wb/xsA reads done; outputs visible
    const ushort_t* Wn = (pj==0 ? Wkt : pj==1 ? Wvt : Wot);
    *(uint4*)&Wb[wr][wc]    = *(const uint4*)&Wn[(size_t)wr*64 + wc];
    *(uint4*)&Wb[wr+32][wc] = *(const uint4*)&Wn[(size_t)(wr+32)*64 + wc];
    if (pj < 2) __syncthreads();
    // pj==2: Wo load covered by later barriers
  }

  // ---- scores via one 32x32x16 MFMA per (node,head); in-reg softmax ----
  float pr[2][12];
#pragma unroll
  for (int gi = 0; gi < 2; gi++){
    int g = w*2 + gi;
    int node = g >> 2, hh = g & 3;
    accv16 s = {};
    frag8 af = *(const frag8*)&qs[node*24 + l31][hh*16 + lh*8];
    frag8 bf = *(const frag8*)&ks[node*24 + l31][hh*16 + lh*8];
    s = __builtin_amdgcn_mfma_f32_32x32x16_bf16(af, bf, s, 0, 0, 0);
    bool cok = (l31 < 24);
#pragma unroll
    for (int r = 0; r < 12; r++){        // rows 24..31 (r>=12) discarded
      float v = cok ? s[r]*0.25f : -1e30f;
      float mx = v;
#pragma unroll
      for (int off = 1; off <= 16; off <<= 1) mx = fmaxf(mx, __shfl_xor(mx, off, 64));
      float e = cok ? __expf(v - mx) : 0.f;
      float sm = e;
#pragma unroll
      for (int off = 1; off <= 16; off <<= 1) sm += __shfl_xor(sm, off, 64);
      pr[gi][r] = e / sm;
    }
  }
  __syncthreads();                       // all qs/ks reads drained
  // zero psb (16384 B), then write valid P entries
  {
    uint4 z4 = {0,0,0,0};
#pragma unroll
    for (int i = 0; i < 4; i++)
      *(uint4*)(smem + 18432 + (tid + i*256)*16) = z4;
  }
  __syncthreads();
#pragma unroll
  for (int gi = 0; gi < 2; gi++){
    int g = w*2 + gi;
    if (l31 < 24){
#pragma unroll
      for (int r = 0; r < 12; r++){
        int row = (r & 3) + 8*(r >> 2) + 4*lh;   // < 24
        psb[g*32 + row][l31] = f2us(pr[gi][r]);
      }
    }
  }
  __syncthreads();

  // ---- PV via 2 MFMAs per group; att -> xsA (A-layout) ----
#pragma unroll
  for (int gi = 0; gi < 2; gi++){
    int g = w*2 + gi;
    int node = g >> 2, hh = g & 3;
    accv16 a = {};
#pragma unroll
    for (int kh = 0; kh < 2; kh++){
      frag8 af = *(const frag8*)&psb[g*32 + l31][kh*16 + lh*8];
      frag8 bf = *(const frag8*)&vsT[g*32 + l31][kh*16 + lh*8];
      a = __builtin_amdgcn_mfma_f32_32x32x16_bf16(af, bf, a, 0, 0, 0);
    }
    if (l31 < 16){
#pragma unroll
      for (int r = 0; r < 12; r++){
        int row = (r & 3) + 8*(r >> 2) + 4*lh;   // < 24
        xsA[node*24 + row][hh*16 + l31] = f2us(a[r]);
      }
    }
  }
  __syncthreads();                       // psb/vsT reads drained; att visible

  // ---- Wo MFMA ----
  accv16 ao = {};
#pragma unroll
  for (int kk = 0; kk < 64; kk += 16){
    frag8 af = *(const frag8*)&xsA[mt + l31][kk + lh*8];
    frag8 bf = *(const frag8*)&Wb[nt + l31][kk + lh*8];
    ao = __builtin_amdgcn_mfma_f32_32x32x16_bf16(af, bf, ao, 0, 0, 0);
  }
  {
    float bov = bo[nt + l31];
#pragma unroll
    for (int r = 0; r < 16; r++){
      int row = mt + (r & 3) + 8*(r >> 2) + 4*lh;
      Os[row][nt + l31] = ao[r] + bov;
    }
  }
  __syncthreads();
  // ---- residual (exact fp32 x re-read) + LN + store ----
  {
    float gv = g_t[lane], bvv = b_t[lane];
#pragma unroll
    for (int i = 0; i < 12; i++){
      int row = w + i*4;
      int node = row / 24, t = row - node*24;
      size_t gaddr = (((size_t)b*T_ + t)*N_ + n0 + node)*D_ + lane;
      float v = Os[row][lane] + x[gaddr];
      float m = wave_sum(v) * (1.f/64.f);
      float df = v - m;
      float var = wave_sum(df*df) * (1.f/64.f);
      h1[gaddr] = df * rsqrtf(var + 1e-5f) * gv + bvv;
    }
  }
}

// ---------- MFMA prop: Y = Ahat@X (per slice), fused G (+)= Y@gcWk ----------
template<typename TX>
__global__ __launch_bounds__(256, 4) void k_prop_m(
    const ushort_t* __restrict__ Ahat,  // [512][512] bf16
    const TX* __restrict__ X,           // [BT][512][64]
    const float* __restrict__ gcWk,     // [64][64] fp32
    ushort_t* __restrict__ P,
    ushort_t* __restrict__ G,
    int store_p, int accum)
{
  __shared__ __align__(16) ushort_t Ab[64][72];
  __shared__ __align__(16) ushort_t Xb[64][72];
  __shared__ __align__(16) ushort_t Yt[64][72];
  __shared__ __align__(16) ushort_t Wt[64][72];
  int tid  = threadIdx.x;
  int lane = tid & 63, w = tid >> 6;
  int mw = (w >> 1) * 32, nw = (w & 1) * 32;
  int l31 = lane & 31, lh = lane >> 5;
  int m0 = blockIdx.x * 64;
  size_t slice = (size_t)blockIdx.y * (N_ * D_);
  const TX* Xg = X + slice;

  {
    int d = tid & 63, e4 = tid >> 6;
#pragma unroll
    for (int g = 0; g < 2; g++){
      int es = (e4 + g*4) * 8;
      ushort_t tmp[8];
#pragma unroll
      for (int i = 0; i < 8; i++) tmp[i] = f2us(gcWk[(es + i)*64 + d]);
      *(uint4*)&Wt[d][es] = *(uint4*)tmp;
    }
  }

  accv16 acc = {};
  int ar = tid >> 3, ac8 = (tid & 7) * 8;
  int xn = tid & 63, xk4 = tid >> 6;
  for (int k0 = 0; k0 < N_; k0 += 64){
#pragma unroll
    for (int g = 0; g < 2; g++){
      int rr = ar + g*32;
      *(uint4*)&Ab[rr][ac8] =
        *(const uint4*)&Ahat[(size_t)(m0 + rr)*N_ + k0 + ac8];
    }
#pragma unroll
    for (int g = 0; g < 2; g++){
      int ks = (xk4 + g*4) * 8;
      ushort_t tmp[8];
#pragma unroll
      for (int i = 0; i < 8; i++) tmp[i] = f2us(ldX(Xg[(size_t)(k0 + ks + i)*D_ + xn]));
      *(uint4*)&Xb[xn][ks] = *(uint4*)tmp;
    }
    __syncthreads();
#pragma unroll
    for (int kk = 0; kk < 64; kk += 16){
      frag8 af = *(const frag8*)&Ab[mw + l31][kk + lh*8];
      frag8 bf = *(const frag8*)&Xb[nw + l31][kk + lh*8];
      acc = __builtin_amdgcn_mfma_f32_32x32x16_bf16(af, bf, acc, 0, 0, 0);
    }
    __syncthreads();
  }

#pragma unroll
  for (int r = 0; r < 16; r++){
    int row = mw + (r & 3) + 8*(r >> 2) + 4*lh;
    Yt[row][nw + l31] = f2us(acc[r]);
  }
  __syncthreads();

  if (store_p){
#pragma unroll
    for (int g = 0; g < 2; g++){
      int rr = ar + g*32;
      *(uint4*)&P[slice + (size_t)(m0 + rr)*D_ + ac8] = *(const uint4*)&Yt[rr][ac8];
    }
  }

  accv16 acc2 = {};
#pragma unroll
  for (int kk = 0; kk < 64; kk += 16){
    frag8 af = *(const frag8*)&Yt[mw + l31][kk + lh*8];
    frag8 bf = *(const frag8*)&Wt[nw + l31][kk + lh*8];
    acc2 = __builtin_amdgcn_mfma_f32_32x32x16_bf16(af, bf, acc2, 0, 0, 0);
  }
#pragma unroll
  for (int r = 0; r < 16; r++){
    int row = mw + (r & 3) + 8*(r >> 2) + 4*lh;
    Ab[row][nw + l31] = f2us(acc2[r]);
  }
  __syncthreads();
#pragma unroll
  for (int g = 0; g < 2; g++){
    int rr = ar + g*32;
    uint4 vv = *(const uint4*)&Ab[rr][ac8];
    size_t base = slice + (size_t)(m0 + rr)*D_ + ac8;
    if (accum){
      uint4 ov = *(const uint4*)&G[base];
      ushort_t* s = (ushort_t*)&vv;
      ushort_t* o = (ushort_t*)&ov;
      ushort_t res[8];
#pragma unroll
      for (int i = 0; i < 8; i++) res[i] = f2us(us2f(s[i]) + us2f(o[i]));
      *(uint4*)&G[base] = *(uint4*)res;
    } else {
      *(uint4*)&G[base] = vv;
    }
  }
}

// ---------- h2 = LN(h1 + h1@gcW0 + g12 + sum(gcb)) ; in-place on d_out ----------
__global__ __launch_bounds__(256) void k_comb(
  const ushort_t* __restrict__ g12,
  const float* __restrict__ gcW, const float* __restrict__ gcb,
  const float* __restrict__ g_g, const float* __restrict__ b_g,
  float* __restrict__ h)
{
  __shared__ float hs[32][64];
  int tid = threadIdx.x;
  size_t tok0 = (size_t)blockIdx.x * 32;
#pragma unroll
  for (int i = 0; i < 8; i++){
    int idx = tid + i*256;
    int dd = idx & 63, t = idx >> 6;
    hs[t][dd] = h[(tok0 + t)*64 + dd];
  }
  __syncthreads();
  int d = tid & 63, trow = tid >> 6;
  float acc[8];
  float bsum = gcb[d] + gcb[64+d] + gcb[128+d];
#pragma unroll
  for (int i = 0; i < 8; i++) acc[i] = bsum + us2f(g12[(tok0 + trow + i*4)*64 + d]);
  for (int e0 = 0; e0 < 64; e0 += 16){
    float w0[16];
#pragma unroll
    for (int j = 0; j < 16; j++) w0[j] = gcW[(e0+j)*64 + d];
#pragma unroll
    for (int i = 0; i < 8; i++){
      int t = trow + i*4;
#pragma unroll
      for (int j = 0; j < 16; j++) acc[i] = fmaf(hs[t][e0+j], w0[j], acc[i]);
    }
  }
  float gv = g_g[d], bv = b_g[d];
#pragma unroll
  for (int i = 0; i < 8; i++){
    int t = trow + i*4;
    float v = acc[i] + hs[t][d];
    float m = wave_sum(v) * (1.f/64.f);
    float df = v - m;
    float var = wave_sum(df*df) * (1.f/64.f);
    float y = df * rsqrtf(var + 1e-5f) * gv + bv;
    h[(tok0 + t)*64 + d] = y;
  }
}

// ---------- MFMA FFN: out = LN(h + gelu(h@W1+b1)@W2 + b2) ; in-place ----------
__global__ __launch_bounds__(256, 4) void k_ffn_m(
  const ushort_t* __restrict__ W1t,   // [256 f][64 e] bf16
  const ushort_t* __restrict__ W2t,   // [64 d][256 e] bf16
  const float* __restrict__ b1, const float* __restrict__ b2,
  const float* __restrict__ g_f, const float* __restrict__ b_f,
  float* __restrict__ h)
{
  __shared__ __align__(16) char smem[9216 + 18432 + 17408];
  ushort_t (*hsA)[72]  = (ushort_t(*)[72]) smem;
  ushort_t (*W1c)[72]  = (ushort_t(*)[72]) (smem + 9216);
  ushort_t (*W2c)[136] = (ushort_t(*)[136])(smem + 9216);
  ushort_t (*Uc)[136]  = (ushort_t(*)[136])(smem + 9216 + 18432);
  float    (*Os)[65]   = (float(*)[65])    (smem + 9216 + 18432);

  int tid = threadIdx.x;
  int lane = tid & 63, w = tid >> 6;
  int l31 = lane & 31, lh = lane >> 5;
  size_t tok0 = (size_t)blockIdx.x * 64;

#pragma unroll
  for (int i = 0; i < 16; i++){
    int idx = tid + i*256;
    int t = idx >> 6, dd = idx & 63;
    hsA[t][dd] = f2us(h[tok0*64 + idx]);
  }

  int mw1 = (w & 1) * 32;
  int nA  = (w >> 1) * 32;
  int mw2 = (w >> 1) * 32;
  int dw  = (w & 1) * 32;
  accv16 acc2 = {};

  for (int f0 = 0; f0 < F_; f0 += 128){
    __syncthreads();
    {
      int row = tid >> 1, half = (tid & 1) * 32;
      const ushort_t* src = &W1t[(size_t)(f0 + row)*64 + half];
#pragma unroll
      for (int g = 0; g < 4; g++)
        *(uint4*)&W1c[row][half + g*8] = *(const uint4*)&src[g*8];
    }
    __syncthreads();
    accv16 accA = {}, accB = {};
#pragma unroll
    for (int kk = 0; kk < 64; kk += 16){
      frag8 af = *(const frag8*)&hsA[mw1 + l31][kk + lh*8];
      frag8 b0 = *(const frag8*)&W1c[nA + l31][kk + lh*8];
      frag8 b1f = *(const frag8*)&W1c[nA + 64 + l31][kk + lh*8];
      accA = __builtin_amdgcn_mfma_f32_32x32x16_bf16(af, b0, accA, 0, 0, 0);
      accB = __builtin_amdgcn_mfma_f32_32x32x16_bf16(af, b1f, accB, 0, 0, 0);
    }
    {
      float bA = b1[f0 + nA + l31];
      float bB = b1[f0 + nA + 64 + l31];
#pragma unroll
      for (int r = 0; r < 16; r++){
        int row = mw1 + (r & 3) + 8*(r >> 2) + 4*lh;
        float uA = accA[r] + bA;
        float uB = accB[r] + bB;
        Uc[row][nA + l31]      = f2us(0.5f*uA*(1.f + erff(uA*0.70710678118654752f)));
        Uc[row][nA + 64 + l31] = f2us(0.5f*uB*(1.f + erff(uB*0.70710678118654752f)));
      }
    }
    __syncthreads();
    {
      int row = tid >> 2, seg = (tid & 3) * 32;
      const ushort_t* src = &W2t[(size_t)row*256 + f0 + seg];
#pragma unroll
      for (int g = 0; g < 4; g++)
        *(uint4*)&W2c[row][seg + g*8] = *(const uint4*)&src[g*8];
    }
    __syncthreads();
#pragma unroll
    for (int kk = 0; kk < 128; kk += 16){
      frag8 af = *(const frag8*)&Uc[mw2 + l31][kk + lh*8];
      frag8 bf = *(const frag8*)&W2c[dw + l31][kk + lh*8];
      acc2 = __builtin_amdgcn_mfma_f32_32x32x16_bf16(af, bf, acc2, 0, 0, 0);
    }
  }
  __syncthreads();
  {
    float b2v = b2[dw + l31];
#pragma unroll
    for (int r = 0; r < 16; r++){
      int row = mw2 + (r & 3) + 8*(r >> 2) + 4*lh;
      Os[row][dw + l31] = acc2[r] + b2v;
    }
  }
  __syncthreads();
  {
    int d = tid & 63, trow = tid >> 6;
    float gv = g_f[d], bv = b_f[d];
#pragma unroll
    for (int i = 0; i < 16; i++){
      int t = trow + i*4;
      float v = Os[t][d] + h[(tok0 + t)*64 + d];
      float m = wave_sum(v) * (1.f/64.f);
      float df = v - m;
      float var = wave_sum(df*df) * (1.f/64.f);
      float y = df * rsqrtf(var + 1e-5f) * gv + bv;
      h[(tok0 + t)*64 + d] = y;
    }
  }
}

extern "C" void kernel_launch(void* const* d_in, const int* in_sizes, int n_in,
                              void* d_out, int out_size, void* d_ws, size_t ws_size,
                              hipStream_t stream)
{
  const float* x   = (const float*)d_in[0];
  const float* adj = (const float*)d_in[1];
  const float* Wq  = (const float*)d_in[2];
  const float* bq  = (const float*)d_in[3];
  const float* Wk  = (const float*)d_in[4];
  const float* bk  = (const float*)d_in[5];
  const float* Wv  = (const float*)d_in[6];
  const float* bv  = (const float*)d_in[7];
  const float* Wo  = (const float*)d_in[8];
  const float* bo  = (const float*)d_in[9];
  const float* gcW = (const float*)d_in[10];
  const float* gcb = (const float*)d_in[11];
  const float* W1  = (const float*)d_in[12];
  const float* b1  = (const float*)d_in[13];
  const float* W2  = (const float*)d_in[14];
  const float* b2  = (const float*)d_in[15];
  const float* g_t = (const float*)d_in[16];
  const float* b_t = (const float*)d_in[17];
  const float* g_g = (const float*)d_in[18];
  const float* b_g = (const float*)d_in[19];
  const float* g_f = (const float*)d_in[20];
  const float* b_f = (const float*)d_in[21];

  // ws (~51 MB): dinv 2KB | Ahat bf16 512KB | p 25.2MB | g12 25.2MB | W1t/W2t 64KB | Wqt..Wot 32KB
  const size_t MD = (size_t)B_*T_*N_*D_;
  float* dinv = (float*)d_ws;
  ushort_t* AhatB = (ushort_t*)(dinv + 512);
  ushort_t* p   = AhatB + (size_t)N_*N_;
  ushort_t* g12 = p + MD;
  ushort_t* W1t = g12 + MD;
  ushort_t* W2t = W1t + 256*64;
  ushort_t* Wqt = W2t + 64*256;
  ushort_t* Wkt = Wqt + 4096;
  ushort_t* Wvt = Wkt + 4096;
  ushort_t* Wot = Wvt + 4096;
  float* h = (float*)d_out;

  k_dinv<<<N_, 64, 0, stream>>>(adj, dinv);
  k_ahat<<<(N_*N_)/256, 256, 0, stream>>>(adj, dinv, AhatB);
  k_wprep<<<64, 256, 0, stream>>>(W1, W2, Wq, Wk, Wv, Wo, W1t, W2t, Wqt, Wkt, Wvt, Wot);
  k_attn_m<<<B_*N_/2, 256, 0, stream>>>(x, Wqt,bq, Wkt,bk, Wvt,bv, Wot,bo, g_t,b_t, h);
  k_prop_m<float><<<dim3(N_/64, B_*T_), 256, 0, stream>>>(AhatB, h, gcW + 4096, p, g12, 1, 0);
  k_prop_m<ushort_t><<<dim3(N_/64, B_*T_), 256, 0, stream>>>(AhatB, p, gcW + 8192, p, g12, 0, 1);
  k_comb<<<(int)(MD/D_/32), 256, 0, stream>>>(g12, gcW, gcb, g_g, b_g, h);
  k_ffn_m<<<(int)(MD/D_/64), 256, 0, stream>>>(W1t, W2t, b1, b2, g_f, b_f, h);
}